// Round 10
// baseline (194.413 us; speedup 1.0000x reference)
//
#include <hip/hip_runtime.h>
#include <cstdint>

#define NTOT 242991
#define BATCH 8
#define KTOT 8741           // 2000*4 + 741
#define CAP 8192            // candidate buffer per (b,level)
#define NBIN 4096           // level-1 histogram bins (top 12 ordered bits)
#define CSTR 16             // counter padding stride
#define MEMTOT 1943928      // sum over levels of B*3*H*W  (== BATCH*NTOT)
#define SLICE 256           // suppression-matrix slice
#define RSTR 9              // rows stride (odd -> conflict-free)
#define BCAP 2048           // batch capacity (keys)
#define NB2 2048            // level-2 bins: rank(3b) x 8 bits

__device__ __forceinline__ int level_of(int n) {
    if (n < 182400) return 0;
    if (n < 228000) return 1;
    if (n < 239400) return 2;
    if (n < 242250) return 3;
    return 4;
}

__device__ __forceinline__ void locate(int n, int& l, int& H, int& W, int& loc) {
    if (n < 182400)      { l = 0; H = 200; W = 304; loc = n; }
    else if (n < 228000) { l = 1; H = 100; W = 152; loc = n - 182400; }
    else if (n < 239400) { l = 2; H = 50;  W = 76;  loc = n - 228000; }
    else if (n < 242250) { l = 3; H = 25;  W = 38;  loc = n - 239400; }
    else                 { l = 4; H = 13;  W = 19;  loc = n - 242250; }
}

__device__ __forceinline__ int classify_bl(int x) {
    int l, HW;
    if (x < 1459200)      { l = 0; HW = 60800; }
    else if (x < 1824000) { l = 1; HW = 15200; x -= 1459200; }
    else if (x < 1915200) { l = 2; HW = 3800;  x -= 1824000; }
    else if (x < 1938000) { l = 3; HW = 950;   x -= 1915200; }
    else                  { l = 4; HW = 247;   x -= 1938000; }
    return (x / (3 * HW)) * 5 + l;
}

__device__ __forceinline__ void mem_decompose(int x, int& b, int& n, int& bl) {
    int HW, off, l;
    if (x < 1459200)      { l = 0; HW = 60800; off = 0; }
    else if (x < 1824000) { l = 1; HW = 15200; off = 182400; x -= 1459200; }
    else if (x < 1915200) { l = 2; HW = 3800;  off = 228000; x -= 1824000; }
    else if (x < 1938000) { l = 3; HW = 950;   off = 239400; x -= 1915200; }
    else                  { l = 4; HW = 247;   off = 242250; x -= 1938000; }
    int seg = 3 * HW;
    b = x / seg; int r = x - b * seg;
    int a = r / HW, pix = r - a * HW;
    n = off + pix * 3 + a;
    bl = b * 5 + l;
}

__device__ __forceinline__ float read_cls(int gid, const float* c0, const float* c1,
                                          const float* c2, const float* c3, const float* c4) {
    return (gid < 1459200) ? c0[gid] :
           (gid < 1824000) ? c1[gid - 1459200] :
           (gid < 1915200) ? c2[gid - 1824000] :
           (gid < 1938000) ? c3[gid - 1915200] : c4[gid - 1938000];
}

// block-wide (1024 thr) inclusive SUFFIX scan (u32); 2 barriers
__device__ __forceinline__ uint32_t suffix_scan_1024(uint32_t g, uint32_t* lds16, int t) {
    int lane = t & 63, wid = t >> 6;
    uint32_t v = g;
#pragma unroll
    for (int o = 1; o < 64; o <<= 1) {
        uint32_t oth = __shfl_down(v, o, 64);
        if (lane + o < 64) v += oth;
    }
    if (lane == 0) lds16[wid] = v;
    __syncthreads();
    uint32_t w = 0;
    for (int q = wid + 1; q < 16; q++) w += lds16[q];
    __syncthreads();
    return v + w;
}

// block-wide inclusive SUFFIX scan (u64); 2 barriers
__device__ __forceinline__ unsigned long long suffix_scan64(unsigned long long g,
                                                            unsigned long long* lds64, int t) {
    int lane = t & 63, wid = t >> 6;
    unsigned long long v = g;
#pragma unroll
    for (int o = 1; o < 64; o <<= 1) {
        unsigned long long oth = __shfl_down(v, o, 64);
        if (lane + o < 64) v += oth;
    }
    if (lane == 0) lds64[wid] = v;
    __syncthreads();
    unsigned long long w = 0;
    for (int q = wid + 1; q < 16; q++) w += lds64[q];
    __syncthreads();
    return v + w;
}

// block-wide inclusive PREFIX scan (u32); 2 barriers
__device__ __forceinline__ uint32_t prefix_scan_1024(uint32_t g, uint32_t* lds16, int t) {
    int lane = t & 63, wid = t >> 6;
    uint32_t v = g;
#pragma unroll
    for (int o = 1; o < 64; o <<= 1) {
        uint32_t oth = __shfl_up(v, o, 64);
        if (lane >= o) v += oth;
    }
    if (lane == 63) lds16[wid] = v;
    __syncthreads();
    uint32_t w = 0;
    for (int q = 0; q < wid; q++) w += lds16[q];
    __syncthreads();
    return v + w;
}

__device__ __forceinline__ bool iou_hit(float bx1, float by1, float bx2, float by2, float ca,
                                        float4 sv) {
    float xx1 = fmaxf(bx1, sv.x), yy1 = fmaxf(by1, sv.y);
    float xx2 = fminf(bx2, sv.z), yy2 = fminf(by2, sv.w);
    float inter = fmaxf(xx2 - xx1, 0.f) * fmaxf(yy2 - yy1, 0.f);
    float sa = (sv.z - sv.x) * (sv.w - sv.y);
    float un = ca + sa - inter;
    return (un > 0.f) && (inter / un > 0.7f);
}

// ---- kernel 1: per-(b,l) score histogram ----
__global__ __launch_bounds__(1024)
void k_keys(const float* __restrict__ c0, const float* __restrict__ c1,
            const float* __restrict__ c2, const float* __restrict__ c3,
            const float* __restrict__ c4, uint32_t* __restrict__ hist) {
    int t = threadIdx.x;
    int base = blockIdx.x * 1024;
    int gid = base + t;
    bool in = gid < MEMTOT;
    __shared__ uint32_t lh[NBIN];

    int bl = 0, b, n;
    uint32_t u = 0;
    if (in) {
        mem_decompose(gid, b, n, bl);
        float sv = read_cls(gid, c0, c1, c2, c3, c4);
        u = __float_as_uint(sv);
        u ^= (u >> 31) ? 0xFFFFFFFFu : 0x80000000u;    // monotonic float->uint
    }
    int blf = classify_bl(base);
    int bll = classify_bl(min(base + 1023, MEMTOT - 1));
    if (blf == bll) {
        for (int j = t; j < NBIN; j += 1024) lh[j] = 0u;
        __syncthreads();
        if (in) atomicAdd(&lh[u >> 20], 1u);
        __syncthreads();
        uint32_t* gh = hist + (size_t)blf * NBIN;
        for (int j = t; j < NBIN; j += 1024) {
            uint32_t v = lh[j];
            if (v) atomicAdd(&gh[j], v);
        }
    } else {
        if (in) atomicAdd(&hist[(size_t)bl * NBIN + (u >> 20)], 1u);
    }
}

// ---- kernel 2: per-(b,l) threshold bin + remainder ----
__global__ void k_bins(const uint32_t* __restrict__ hist, int* __restrict__ binT,
                       int* __restrict__ rrem) {
    int bl = blockIdx.x;             // 40 blocks
    const uint32_t* h = hist + (size_t)bl * NBIN;
    int l = bl % 5;
    uint32_t k = (l == 4) ? 741u : 2000u;
    __shared__ uint32_t ts[256];
    __shared__ uint32_t sb[256];
    int t = threadIdx.x;             // 256 threads, 16 bins each
    uint32_t hh[16];
#pragma unroll
    for (int i = 0; i < 16; i++) hh[i] = h[t * 16 + i];
    uint32_t s = 0;
#pragma unroll
    for (int i = 0; i < 16; i++) s += hh[i];
    ts[t] = s; sb[t] = s;
    __syncthreads();
    for (int d = 1; d < 256; d <<= 1) {
        uint32_t add = (t + d < 256) ? sb[t + d] : 0u;
        __syncthreads();
        sb[t] += add;
        __syncthreads();
    }
    uint32_t inc = sb[t], excl = inc - ts[t];
    if (excl < k && inc >= k) {
        uint32_t cum = excl;
#pragma unroll
        for (int i = 15; i >= 0; i--) {
            if (cum + hh[i] >= k) { binT[bl] = t * 16 + i; rrem[bl] = (int)(k - cum); break; }
            cum += hh[i];
        }
    }
}

// ---- kernel 3: wide compact from cls (mem-order, recompute key) ----
__global__ __launch_bounds__(1024)
void k_compact(const float* __restrict__ c0, const float* __restrict__ c1,
               const float* __restrict__ c2, const float* __restrict__ c3,
               const float* __restrict__ c4, const int* __restrict__ binT,
               uint32_t* __restrict__ keep_n, uint32_t* __restrict__ keep_u,
               uint32_t* __restrict__ keep_cnt,
               uint32_t* __restrict__ cand_n, uint32_t* __restrict__ cand_u,
               uint32_t* __restrict__ cand_cnt) {
    int gid = blockIdx.x * 1024 + threadIdx.x;
    bool in = gid < MEMTOT;
    int b = 0, n = 0, bl = 0;
    uint32_t u = 0;
    if (in) {
        mem_decompose(gid, b, n, bl);
        float sv = read_cls(gid, c0, c1, c2, c3, c4);
        u = __float_as_uint(sv);
        u ^= (u >> 31) ? 0xFFFFFFFFu : 0x80000000u;
    }
    int T = in ? binT[bl] : 0x7FFFFFFF;
    int bin = (int)(u >> 20);
    bool pk = in && (bin > T);
    bool pc = in && (bin == T);
    int lane = threadIdx.x & 63;

    unsigned long long act = __ballot(in);
    if (act == 0ull) return;
    int lead = __ffsll(act) - 1;
    int bl0 = __shfl(bl, lead, 64);
    bool unif = (__ballot(in && (bl == bl0)) == act);
    if (unif) {
        int b0 = bl0 / 5, l0 = bl0 % 5;
        uint32_t kbase = (uint32_t)(b0 * KTOT + l0 * 2000);
        unsigned long long mk = __ballot(pk);
        if (mk) {
            int leader = __ffsll(mk) - 1;
            uint32_t bs = 0;
            if (lane == leader) bs = atomicAdd(&keep_cnt[bl0 * CSTR], (uint32_t)__popcll(mk));
            bs = __shfl(bs, leader, 64);
            if (pk) {
                uint32_t p = kbase + bs + (uint32_t)__popcll(mk & ((1ull << lane) - 1ull));
                keep_n[p] = (uint32_t)n; keep_u[p] = u;
            }
        }
        unsigned long long mc = __ballot(pc);
        if (mc) {
            int leader = __ffsll(mc) - 1;
            uint32_t bs = 0;
            if (lane == leader) bs = atomicAdd(&cand_cnt[bl0 * CSTR], (uint32_t)__popcll(mc));
            bs = __shfl(bs, leader, 64);
            if (pc) {
                uint32_t p = bs + (uint32_t)__popcll(mc & ((1ull << lane) - 1ull));
                if (p < CAP) {
                    cand_n[(size_t)bl0 * CAP + p] = (uint32_t)n;
                    cand_u[(size_t)bl0 * CAP + p] = u;
                }
            }
        }
    } else {
        int b1 = bl / 5, l1 = bl % 5;
        if (pk) {
            uint32_t p = atomicAdd(&keep_cnt[bl * CSTR], 1u);
            uint32_t q = (uint32_t)(b1 * KTOT + l1 * 2000) + p;
            keep_n[q] = (uint32_t)n; keep_u[q] = u;
        }
        if (pc) {
            uint32_t p = atomicAdd(&cand_cnt[bl * CSTR], 1u);
            if (p < CAP) {
                cand_n[(size_t)bl * CAP + p] = (uint32_t)n;
                cand_u[(size_t)bl * CAP + p] = u;
            }
        }
    }
}

// ---- kernel 4: exact radix select over boundary candidates (52-bit, 5 passes) ----
__global__ __launch_bounds__(1024)
void k_select(const uint32_t* __restrict__ cand_n, const uint32_t* __restrict__ cand_u,
              const uint32_t* __restrict__ cand_cnt, const int* __restrict__ rrem,
              uint32_t* __restrict__ keep_n, uint32_t* __restrict__ keep_u,
              uint32_t* __restrict__ keep_cnt) {
    int bl = blockIdx.x;             // 40 blocks x 1024 threads
    int b = bl / 5, l = bl % 5;
    int C = (int)min(cand_cnt[bl * CSTR], (uint32_t)CAP);
    int r = rrem[bl];
    const uint32_t* cdn = cand_n + (size_t)bl * CAP;
    const uint32_t* cdu = cand_u + (size_t)bl * CAP;
    __shared__ uint32_t hist_l[2048];
    __shared__ uint32_t lds16[16];
    __shared__ unsigned long long pref_sh;
    __shared__ uint32_t kk_sh;
    int t = threadIdx.x;
    if (t == 0) { pref_sh = 0ull; kk_sh = (uint32_t)r; }
    unsigned long long maskAcc = 0ull;
    const int shifts[5] = {41, 30, 19, 8, 0};
    const uint32_t masks[5] = {0x7FFu, 0x7FFu, 0x7FFu, 0x7FFu, 0xFFu};
    __syncthreads();
    for (int p = 0; p < 5; p++) {
        int shift = shifts[p];
        uint32_t msk = masks[p];
        for (int j = t; j < 2048; j += 1024) hist_l[j] = 0u;
        __syncthreads();
        unsigned long long pref = pref_sh;
        uint32_t kk = kk_sh;
        for (int i = t; i < C; i += 1024) {
            unsigned long long key =
                ((unsigned long long)cdu[i] << 32) | (uint32_t)(~cdn[i]);
            if ((key & maskAcc) == pref)
                atomicAdd(&hist_l[(uint32_t)(key >> shift) & msk], 1u);
        }
        __syncthreads();
        uint32_t g = hist_l[2 * t] + hist_l[2 * t + 1];
        uint32_t inc = suffix_scan_1024(g, lds16, t);
        uint32_t excl = inc - g;
        if (excl < kk && inc >= kk) {
            uint32_t hh1 = hist_l[2 * t + 1];
            uint32_t digit, rem;
            if (excl + hh1 >= kk) { digit = 2 * t + 1; rem = kk - excl; }
            else { digit = 2 * t; rem = kk - (excl + hh1); }
            pref_sh = pref | ((unsigned long long)digit << shift);
            kk_sh = rem;
        }
        __syncthreads();
        maskAcc |= (unsigned long long)msk << shift;
    }
    unsigned long long Tk = pref_sh;
    __syncthreads();
    int lane = t & 63;
    for (int i0 = 0; i0 < C; i0 += 1024) {
        int i = i0 + t;
        bool in = i < C;
        uint32_t n = in ? cdn[i] : 0u;
        uint32_t u = in ? cdu[i] : 0u;
        unsigned long long key = in ?
            (((unsigned long long)u << 32) | (uint32_t)(~n)) : 0ull;
        bool pr = in && ((key & maskAcc) >= Tk);
        unsigned long long mk = __ballot(pr);
        if (mk) {
            int leader = __ffsll(mk) - 1;
            uint32_t bs = 0;
            if (lane == leader) bs = atomicAdd(&keep_cnt[bl * CSTR], (uint32_t)__popcll(mk));
            bs = __shfl(bs, leader, 64);
            if (pr) {
                uint32_t p = (uint32_t)(b * KTOT + l * 2000) + bs +
                             (uint32_t)__popcll(mk & ((1ull << lane) - 1ull));
                keep_n[p] = n; keep_u[p] = u;
            }
        }
    }
}

// ---- kernel 5: WIDE decode + clip + validity + bucket histogram ----
__global__ void k_decode(const float* __restrict__ b0, const float* __restrict__ b1,
                         const float* __restrict__ b2, const float* __restrict__ b3,
                         const float* __restrict__ b4, const float* __restrict__ anchors,
                         const uint32_t* __restrict__ keep_n, const uint32_t* __restrict__ keep_u,
                         float4* __restrict__ nbox, unsigned long long* __restrict__ nkey,
                         uint32_t* __restrict__ shist) {
    int gid = blockIdx.x * blockDim.x + threadIdx.x;
    if (gid >= BATCH * KTOT) return;
    int b = gid / KTOT;
    int n = (int)keep_n[gid];
    uint32_t u = keep_u[gid];
    int l, H, W, loc; locate(n, l, H, W, loc);
    int a = loc % 3, hw = loc / 3;
    int w = hw % W, h = hw / W;
    const float* bp = (l == 0) ? b0 : (l == 1) ? b1 : (l == 2) ? b2 : (l == 3) ? b3 : b4;
    int HW = H * W;
    int base = ((b * 12 + a * 4) * H + h) * W + w;
    float dx = bp[base], dy = bp[base + HW];
    float dw = bp[base + 2 * HW], dh = bp[base + 3 * HW];
    float ax1 = anchors[4 * n], ay1 = anchors[4 * n + 1];
    float ax2 = anchors[4 * n + 2], ay2 = anchors[4 * n + 3];
    float wa = ax2 - ax1, ha = ay2 - ay1;
    float cxa = ax1 + 0.5f * wa, cya = ay1 + 0.5f * ha;
    const float CLIPV = 4.135166556742356f;    // log(1000/16)
    dw = fminf(dw, CLIPV); dh = fminf(dh, CLIPV);
    float cx = dx * wa + cxa, cy = dy * ha + cya;
    float pw = expf(dw) * wa, ph = expf(dh) * ha;
    float x1 = cx - 0.5f * pw, y1 = cy - 0.5f * ph;
    float x2 = cx + 0.5f * pw, y2 = cy + 0.5f * ph;
    x1 = fminf(fmaxf(x1, 0.f), 1216.f); x2 = fminf(fmaxf(x2, 0.f), 1216.f);
    y1 = fminf(fmaxf(y1, 0.f), 800.f);  y2 = fminf(fmaxf(y2, 0.f), 800.f);
    bool valid = ((x2 - x1) >= 1e-3f) && ((y2 - y1) >= 1e-3f);
    float off = (float)l * 1217.0f;            // max(IMG_H,IMG_W)+1
    nbox[gid] = make_float4(x1 + off, y1 + off, x2 + off, y2 + off);
    nkey[gid] = valid ? (((unsigned long long)u << 32) | (uint32_t)(~n)) : 0ull;
    if (valid) atomicAdd(&shist[b * NBIN + (u >> 20)], 1u);
}

// ---- kernel 6: per-image bucket suffix scan -> cursors + nonempty list ----
__global__ __launch_bounds__(1024)
void k_scanbuckets(const uint32_t* __restrict__ shist, uint32_t* __restrict__ scursor,
                   uint32_t* __restrict__ nb_start, uint32_t* __restrict__ nb_cnt,
                   uint32_t* __restrict__ nb_id, uint32_t* __restrict__ nbcnt) {
    int b = blockIdx.x, t = threadIdx.x;
    const uint32_t* h = shist + (size_t)b * NBIN;
    __shared__ unsigned long long lds64[16];
    uint32_t h0 = h[4 * t], h1 = h[4 * t + 1], h2 = h[4 * t + 2], h3 = h[4 * t + 3];
#define PK(c) ((unsigned long long)(c) | ((unsigned long long)((c) > 0u) << 32))
    unsigned long long g = PK(h0) + PK(h1) + PK(h2) + PK(h3);
    unsigned long long inc = suffix_scan64(g, lds64, t);
    unsigned long long acc = inc - g;
    uint32_t* SC = scursor + (size_t)b * NBIN;
    uint32_t* NBS = nb_start + (size_t)b * NBIN;
    uint32_t* NBC = nb_cnt + (size_t)b * NBIN;
    uint32_t* NBI = nb_id + (size_t)b * NBIN;
#define EMIT(q, cq) { int bin = 4 * t + (q); uint32_t st = (uint32_t)acc;            \
                      uint32_t fp = (uint32_t)(acc >> 32);                           \
                      SC[bin] = st;                                                  \
                      if (cq) { NBS[fp] = st; NBC[fp] = cq; NBI[fp] = (uint32_t)bin; } \
                      acc += PK(cq); }
    EMIT(3, h3) EMIT(2, h2) EMIT(1, h1) EMIT(0, h0)
#undef EMIT
#undef PK
    if (t == 0) nbcnt[b] = (uint32_t)(inc >> 32);
}

// ---- kernel 7: WIDE scatter into bucket-descending order ----
__global__ void k_scatter(const unsigned long long* __restrict__ nkey,
                          const float4* __restrict__ nbox,
                          uint32_t* __restrict__ scursor,
                          unsigned long long* __restrict__ skey, float4* __restrict__ sbox) {
    int gid = blockIdx.x * blockDim.x + threadIdx.x;
    if (gid >= BATCH * KTOT) return;
    unsigned long long kk = nkey[gid];
    if (kk == 0ull) return;
    int b = gid / KTOT;
    uint32_t bucket = (uint32_t)(kk >> 52);
    uint32_t p = atomicAdd(&scursor[b * NBIN + bucket], 1u);
    skey[(size_t)b * KTOT + p] = kk;
    sbox[(size_t)b * KTOT + p] = nbox[gid];
}

// ---- kernel 8: two-level bucket-scatter sort + suppression-matrix NMS ----
__global__ __launch_bounds__(1024)
void k_scan(const unsigned long long* __restrict__ skey, const float4* __restrict__ sbox,
            const uint32_t* __restrict__ nb_start, const uint32_t* __restrict__ nb_cnt,
            const uint32_t* __restrict__ nb_id, const uint32_t* __restrict__ nbcnt,
            float* __restrict__ out) {
    int b = blockIdx.x, t = threadIdx.x, lane = t & 63, wid = t >> 6;
    const unsigned long long* SK = skey + (size_t)b * KTOT;
    const float4* BXs = sbox + (size_t)b * KTOT;
    const uint32_t* NBS = nb_start + (size_t)b * NBIN;
    const uint32_t* NBC = nb_cnt + (size_t)b * NBIN;
    const uint32_t* NBI = nb_id + (size_t)b * NBIN;

    __shared__ unsigned long long k_l[BCAP];        // 16 KB sorted keys
    __shared__ unsigned short p_l[BCAP];            // 4 KB payload (scatter idx)
    __shared__ uint32_t hist2[NB2];                 // 8 KB
    __shared__ uint32_t scur2[NB2];                 // 8 KB
    __shared__ unsigned char rnk[NBIN];             // 4 KB bucket->batch-rank
    __shared__ float box_x[SLICE], box_y[SLICE], box_z[SLICE], box_w[SLICE]; // 4 KB
    __shared__ uint32_t rows[SLICE * RSTR];         // 9.2 KB
    __shared__ float4 sel_l[100];                   // 1.6 KB
    __shared__ uint32_t sup[SLICE / 32];
    __shared__ uint32_t lds16[16];
    __shared__ uint32_t picks_sh;
    __shared__ unsigned long long gmax_sh;
    __shared__ uint32_t jpos_sh;
    __shared__ unsigned long long wred[16];

    uint32_t nbc = nbcnt[b];
    uint32_t picks = 0;
    uint32_t e = 0;
    while (e < nbc && picks < 100u) {
        // ---- batch walk (block-uniform; all values from uniform global reads) ----
        uint32_t bstart = NBS[e];
        uint32_t total = 0, nb = 0;
        while (e + nb < nbc && nb < 8u) {
            uint32_t c = NBC[e + nb];
            if (nb > 0u && total + c > (uint32_t)BCAP) break;
            total += c; nb++;
            if (total >= (uint32_t)BCAP) break;
        }

        if (total <= (uint32_t)BCAP) {
            // ---- level-2 bucket scatter (exact descending order) ----
            if (t < (int)nb) rnk[NBI[e + t]] = (unsigned char)t;
            for (int j2 = t; j2 < NB2; j2 += 1024) hist2[j2] = 0u;
            __syncthreads();
            unsigned long long k0 = 0ull, k1 = 0ull;
            uint32_t bin0 = 0xFFFFFFFFu, bin1 = 0xFFFFFFFFu;
            if ((uint32_t)t < total) {
                k0 = SK[bstart + (uint32_t)t];
                bin0 = ((uint32_t)rnk[(uint32_t)(k0 >> 52)] << 8) |
                       (255u - (uint32_t)((k0 >> 44) & 0xFFull));
                atomicAdd(&hist2[bin0], 1u);
            }
            if ((uint32_t)t + 1024u < total) {
                k1 = SK[bstart + (uint32_t)t + 1024u];
                bin1 = ((uint32_t)rnk[(uint32_t)(k1 >> 52)] << 8) |
                       (255u - (uint32_t)((k1 >> 44) & 0xFFull));
                atomicAdd(&hist2[bin1], 1u);
            }
            __syncthreads();
            uint32_t h0 = hist2[2 * t], h1 = hist2[2 * t + 1];
            uint32_t inc = prefix_scan_1024(h0 + h1, lds16, t);
            uint32_t excl = inc - (h0 + h1);
            scur2[2 * t] = excl; scur2[2 * t + 1] = excl + h0;
            __syncthreads();
            if (bin0 != 0xFFFFFFFFu) {
                uint32_t pos = atomicAdd(&scur2[bin0], 1u);
                k_l[pos] = k0; p_l[pos] = (unsigned short)(bstart + (uint32_t)t);
            }
            if (bin1 != 0xFFFFFFFFu) {
                uint32_t pos = atomicAdd(&scur2[bin1], 1u);
                k_l[pos] = k1; p_l[pos] = (unsigned short)(bstart + (uint32_t)t + 1024u);
            }
            __syncthreads();
            // ---- collision fixup: per-bin insertion sort desc (exact) ----
#pragma unroll
            for (int q = 0; q < 2; q++) {
                uint32_t bin = 2 * (uint32_t)t + (uint32_t)q;
                uint32_t c = hist2[bin];
                if (c > 1u) {
                    uint32_t st = scur2[bin] - c;
                    for (uint32_t a = st + 1; a < st + c; a++) {
                        unsigned long long kv = k_l[a]; unsigned short pv = p_l[a];
                        uint32_t w2 = a;
                        while (w2 > st && k_l[w2 - 1] < kv) {
                            k_l[w2] = k_l[w2 - 1]; p_l[w2] = p_l[w2 - 1]; w2--;
                        }
                        k_l[w2] = kv; p_l[w2] = pv;
                    }
                }
            }
            __syncthreads();

            // ---- slices of 256 with precomputed suppression matrix ----
            for (uint32_t s0 = 0; s0 < total && picks < 100u; s0 += SLICE) {
                uint32_t sl = min((uint32_t)SLICE, total - s0);
                if (t < SLICE) {
                    if (t < (int)sl) {
                        float4 cb = BXs[p_l[s0 + t]];
                        box_x[t] = cb.x; box_y[t] = cb.y; box_z[t] = cb.z; box_w[t] = cb.w;
                    } else {
                        box_x[t] = 0.f; box_y[t] = 0.f; box_z[t] = 0.f; box_w[t] = 0.f;
                    }
                }
                if (t < SLICE / 32) sup[t] = 0u;
                __syncthreads();
                // pre-suppression vs already-selected (unrolled x4, no break)
                if (picks > 0u && t < (int)sl) {
                    float bx1 = box_x[t], by1 = box_y[t], bx2 = box_z[t], by2 = box_w[t];
                    float ca = (bx2 - bx1) * (by2 - by1);
                    bool hit = false;
                    uint32_t s = 0;
                    for (; s + 4 <= picks; s += 4) {
                        float4 v0 = sel_l[s], v1 = sel_l[s + 1], v2 = sel_l[s + 2],
                               v3 = sel_l[s + 3];
                        hit = hit | iou_hit(bx1, by1, bx2, by2, ca, v0)
                                  | iou_hit(bx1, by1, bx2, by2, ca, v1)
                                  | iou_hit(bx1, by1, bx2, by2, ca, v2)
                                  | iou_hit(bx1, by1, bx2, by2, ca, v3);
                    }
                    for (; s < picks; s++) hit = hit | iou_hit(bx1, by1, bx2, by2, ca, sel_l[s]);
                    if (hit) atomicOr(&sup[t >> 5], 1u << (t & 31));
                }
                // build suppression matrix
                for (uint32_t widx = t; widx < SLICE * 8; widx += 1024) {
                    uint32_t i = widx & (SLICE - 1);
                    uint32_t wq = widx >> 8;
                    float bx1 = box_x[i], by1 = box_y[i], bx2 = box_z[i], by2 = box_w[i];
                    float ai = (bx2 - bx1) * (by2 - by1);
                    uint32_t jbase = wq * 32u, bits = 0u;
#pragma unroll
                    for (uint32_t qq = 0; qq < 32u; qq++) {
                        uint32_t jj = jbase + qq;
                        float jx1 = box_x[jj], jy1 = box_y[jj],
                              jx2 = box_z[jj], jy2 = box_w[jj];
                        float xx1 = fmaxf(bx1, jx1), yy1 = fmaxf(by1, jy1);
                        float xx2 = fminf(bx2, jx2), yy2 = fminf(by2, jy2);
                        float inter = fmaxf(xx2 - xx1, 0.f) * fmaxf(yy2 - yy1, 0.f);
                        float aj = (jx2 - jx1) * (jy2 - jy1);
                        float un = ai + aj - inter;
                        bool sp = (jj > i) && (un > 0.f) && (inter / un > 0.7f);
                        bits |= ((uint32_t)sp) << qq;
                    }
                    rows[i * RSTR + wq] = bits;
                }
                __syncthreads();
                // greedy sweep by wave 0 (pure bit ops)
                if (wid == 0) {
                    uint32_t myw = (lane < SLICE / 32) ? sup[lane] : 0u;
                    uint32_t pk = picks;
                    for (uint32_t i = 0; i < sl && pk < 100u; i++) {
                        uint32_t wv = __shfl(myw, (int)(i >> 5), 64);
                        if (!((wv >> (i & 31)) & 1u)) {
                            if (lane < SLICE / 32) myw |= rows[i * RSTR + lane];
                            if (lane == 0) {
                                float4 cb = make_float4(box_x[i], box_y[i], box_z[i], box_w[i]);
                                sel_l[pk] = cb;
                                unsigned long long mkey = k_l[s0 + i];
                                uint32_t n = ~(uint32_t)(mkey & 0xFFFFFFFFull);
                                float off = (float)level_of((int)n) * 1217.0f;
                                float* ob = out + ((size_t)b * 100 + pk) * 4;
                                ob[0] = cb.x - off; ob[1] = cb.y - off;
                                ob[2] = cb.z - off; ob[3] = cb.w - off;
                                uint32_t uu = (uint32_t)(mkey >> 32);
                                uint32_t sb2 = (uu & 0x80000000u) ? (uu ^ 0x80000000u) : ~uu;
                                out[3200 + b * 100 + pk] = __uint_as_float(sb2);
                            }
                            pk++;
                        }
                    }
                    if (lane == 0) picks_sh = pk;
                }
                __syncthreads();
                picks = picks_sh;
            }
        } else {
            // exact serial fallback over one oversized bucket (contiguous range)
            unsigned long long last = 0ull;
            bool first = true;
            for (uint32_t done = 0; done < total && picks < 100u; done++) {
                unsigned long long lbest = 0ull;
                uint32_t jbest = 0;
                for (uint32_t jj = bstart + t; jj < bstart + total; jj += 1024) {
                    unsigned long long kk = SK[jj];
                    if ((first || kk < last) && kk > lbest) { lbest = kk; jbest = jj; }
                }
                unsigned long long wm = lbest;
#pragma unroll
                for (int o2 = 32; o2 > 0; o2 >>= 1) {
                    unsigned long long oth = __shfl_down(wm, o2, 64);
                    if (oth > wm) wm = oth;
                }
                if (lane == 0) wred[wid] = wm;
                __syncthreads();
                if (t == 0) {
                    unsigned long long mm = wred[0];
                    for (int q = 1; q < 16; q++) if (wred[q] > mm) mm = wred[q];
                    gmax_sh = mm;
                }
                __syncthreads();
                unsigned long long gm = gmax_sh;
                if (gm == 0ull) break;
                if (lbest == gm) jpos_sh = jbest;
                __syncthreads();
                float4 cb = BXs[jpos_sh];
                float ca = (cb.z - cb.x) * (cb.w - cb.y);
                bool hit = false;
                for (uint32_t s = (uint32_t)lane; s < picks; s += 64u)
                    hit = hit | iou_hit(cb.x, cb.y, cb.z, cb.w, ca, sel_l[s]);
                bool selq = (__ballot(hit) == 0ull);
                if (selq) {
                    if (t == 0) {
                        sel_l[picks] = cb;
                        uint32_t n = ~(uint32_t)(gm & 0xFFFFFFFFull);
                        float off = (float)level_of((int)n) * 1217.0f;
                        float* ob = out + ((size_t)b * 100 + picks) * 4;
                        ob[0] = cb.x - off; ob[1] = cb.y - off;
                        ob[2] = cb.z - off; ob[3] = cb.w - off;
                        uint32_t uu = (uint32_t)(gm >> 32);
                        uint32_t sb2 = (uu & 0x80000000u) ? (uu ^ 0x80000000u) : ~uu;
                        out[3200 + b * 100 + picks] = __uint_as_float(sb2);
                    }
                    picks++;
                }
                last = gm; first = false;
                __syncthreads();
            }
        }
        e += nb;
    }
    // zero-fill unselected output slots
    for (uint32_t i = picks + (uint32_t)t; i < 100u; i += 1024u) {
        float* ob = out + ((size_t)b * 100 + i) * 4;
        ob[0] = 0.f; ob[1] = 0.f; ob[2] = 0.f; ob[3] = 0.f;
        out[3200 + b * 100 + i] = 0.f;
    }
}

extern "C" void kernel_launch(void* const* d_in, const int* in_sizes, int n_in,
                              void* d_out, int out_size, void* d_ws, size_t ws_size,
                              hipStream_t stream) {
    // setup_inputs() order: cls0, box0, cls1, box1, cls2, box2, cls3, box3, cls4, box4, anchors
    const float* cls[5] = { (const float*)d_in[0], (const float*)d_in[2], (const float*)d_in[4],
                            (const float*)d_in[6], (const float*)d_in[8] };
    const float* box[5] = { (const float*)d_in[1], (const float*)d_in[3], (const float*)d_in[5],
                            (const float*)d_in[7], (const float*)d_in[9] };
    const float* anchors = (const float*)d_in[10];
    float* out = (float*)d_out;

    // ---- workspace layout (u32 units). Zero blob first (one memset). ----
    uint32_t* W32 = (uint32_t*)d_ws;
    size_t o = 0;
    uint32_t* hist     = W32 + o; o += (size_t)40 * NBIN;      // 163840
    uint32_t* shist    = W32 + o; o += (size_t)BATCH * NBIN;   // 32768
    uint32_t* keep_cnt = W32 + o; o += 40 * CSTR;              // 640
    uint32_t* cand_cnt = W32 + o; o += 40 * CSTR;              // 640
    size_t zero_n = o;
    int*      binT     = (int*)(W32 + o); o += 64;
    int*      rrem     = (int*)(W32 + o); o += 64;
    uint32_t* nbcnt    = W32 + o; o += 16;
    uint32_t* scursor  = W32 + o; o += (size_t)BATCH * NBIN;
    uint32_t* nb_start = W32 + o; o += (size_t)BATCH * NBIN;
    uint32_t* nb_cnt   = W32 + o; o += (size_t)BATCH * NBIN;
    uint32_t* nb_id    = W32 + o; o += (size_t)BATCH * NBIN;
    uint32_t* keep_n   = W32 + o; o += (size_t)BATCH * KTOT;
    uint32_t* keep_u   = W32 + o; o += (size_t)BATCH * KTOT;
    uint32_t* cand_n   = W32 + o; o += (size_t)40 * CAP;
    uint32_t* cand_u   = W32 + o; o += (size_t)40 * CAP;
    o = (o + 3) & ~(size_t)3;                                  // 16B align
    float4* nbox = (float4*)(W32 + o); o += (size_t)BATCH * KTOT * 4;
    unsigned long long* nkey = (unsigned long long*)(W32 + o); o += (size_t)BATCH * KTOT * 2;
    float4* sbox = (float4*)(W32 + o); o += (size_t)BATCH * KTOT * 4;
    unsigned long long* skey = (unsigned long long*)(W32 + o); o += (size_t)BATCH * KTOT * 2;

    hipMemsetAsync(d_ws, 0, zero_n * sizeof(uint32_t), stream);
    k_keys<<<(MEMTOT + 1023) / 1024, 1024, 0, stream>>>(cls[0], cls[1], cls[2], cls[3], cls[4],
                                                        hist);
    k_bins<<<40, 256, 0, stream>>>(hist, binT, rrem);
    k_compact<<<(MEMTOT + 1023) / 1024, 1024, 0, stream>>>(cls[0], cls[1], cls[2], cls[3],
                                                           cls[4], binT, keep_n, keep_u,
                                                           keep_cnt, cand_n, cand_u, cand_cnt);
    k_select<<<40, 1024, 0, stream>>>(cand_n, cand_u, cand_cnt, rrem, keep_n, keep_u, keep_cnt);
    {
        int tot = BATCH * KTOT;
        k_decode<<<(tot + 255) / 256, 256, 0, stream>>>(box[0], box[1], box[2], box[3], box[4],
                                                        anchors, keep_n, keep_u,
                                                        nbox, nkey, shist);
    }
    k_scanbuckets<<<BATCH, 1024, 0, stream>>>(shist, scursor, nb_start, nb_cnt, nb_id, nbcnt);
    {
        int tot = BATCH * KTOT;
        k_scatter<<<(tot + 255) / 256, 256, 0, stream>>>(nkey, nbox, scursor, skey, sbox);
    }
    k_scan<<<BATCH, 1024, 0, stream>>>(skey, sbox, nb_start, nb_cnt, nb_id, nbcnt, out);
}

// Round 11
// 147.847 us; speedup vs baseline: 1.3150x; 1.3150x over previous
//
#include <hip/hip_runtime.h>
#include <cstdint>

#define NTOT 242991
#define BATCH 8
#define KTOT 8741           // 2000*4 + 741
#define CAP 8192            // candidate buffer per (b,level)
#define NBIN 4096           // level-1 histogram bins (top 12 ordered bits)
#define CSTR 16             // counter padding stride
#define MEMTOT 1943928      // sum over levels of B*3*H*W  (== BATCH*NTOT)
#define SLICE 256           // suppression-matrix slice
#define RSTR 9              // rows stride (odd -> conflict-free)
#define BCAP 2048           // batch capacity (keys)
#define NB2 2048            // level-2 bins
#define DBLK 9              // decode blocks per image: ceil(KTOT/1024)

__device__ __forceinline__ int level_of(int n) {
    if (n < 182400) return 0;
    if (n < 228000) return 1;
    if (n < 239400) return 2;
    if (n < 242250) return 3;
    return 4;
}

__device__ __forceinline__ void locate(int n, int& l, int& H, int& W, int& loc) {
    if (n < 182400)      { l = 0; H = 200; W = 304; loc = n; }
    else if (n < 228000) { l = 1; H = 100; W = 152; loc = n - 182400; }
    else if (n < 239400) { l = 2; H = 50;  W = 76;  loc = n - 228000; }
    else if (n < 242250) { l = 3; H = 25;  W = 38;  loc = n - 239400; }
    else                 { l = 4; H = 13;  W = 19;  loc = n - 242250; }
}

__device__ __forceinline__ int classify_bl(int x) {
    int l, HW;
    if (x < 1459200)      { l = 0; HW = 60800; }
    else if (x < 1824000) { l = 1; HW = 15200; x -= 1459200; }
    else if (x < 1915200) { l = 2; HW = 3800;  x -= 1824000; }
    else if (x < 1938000) { l = 3; HW = 950;   x -= 1915200; }
    else                  { l = 4; HW = 247;   x -= 1938000; }
    return (x / (3 * HW)) * 5 + l;
}

__device__ __forceinline__ void mem_decompose(int x, int& b, int& n, int& bl) {
    int HW, off, l;
    if (x < 1459200)      { l = 0; HW = 60800; off = 0; }
    else if (x < 1824000) { l = 1; HW = 15200; off = 182400; x -= 1459200; }
    else if (x < 1915200) { l = 2; HW = 3800;  off = 228000; x -= 1824000; }
    else if (x < 1938000) { l = 3; HW = 950;   off = 239400; x -= 1915200; }
    else                  { l = 4; HW = 247;   off = 242250; x -= 1938000; }
    int seg = 3 * HW;
    b = x / seg; int r = x - b * seg;
    int a = r / HW, pix = r - a * HW;
    n = off + pix * 3 + a;
    bl = b * 5 + l;
}

__device__ __forceinline__ float read_cls(int gid, const float* c0, const float* c1,
                                          const float* c2, const float* c3, const float* c4) {
    return (gid < 1459200) ? c0[gid] :
           (gid < 1824000) ? c1[gid - 1459200] :
           (gid < 1915200) ? c2[gid - 1824000] :
           (gid < 1938000) ? c3[gid - 1915200] : c4[gid - 1938000];
}

// block-wide (1024 thr) inclusive SUFFIX scan (u32); 2 barriers
__device__ __forceinline__ uint32_t suffix_scan_1024(uint32_t g, uint32_t* lds16, int t) {
    int lane = t & 63, wid = t >> 6;
    uint32_t v = g;
#pragma unroll
    for (int o = 1; o < 64; o <<= 1) {
        uint32_t oth = __shfl_down(v, o, 64);
        if (lane + o < 64) v += oth;
    }
    if (lane == 0) lds16[wid] = v;
    __syncthreads();
    uint32_t w = 0;
    for (int q = wid + 1; q < 16; q++) w += lds16[q];
    __syncthreads();
    return v + w;
}

// block-wide inclusive PREFIX scan (u32); 2 barriers
__device__ __forceinline__ uint32_t prefix_scan_1024(uint32_t g, uint32_t* lds16, int t) {
    int lane = t & 63, wid = t >> 6;
    uint32_t v = g;
#pragma unroll
    for (int o = 1; o < 64; o <<= 1) {
        uint32_t oth = __shfl_up(v, o, 64);
        if (lane >= o) v += oth;
    }
    if (lane == 63) lds16[wid] = v;
    __syncthreads();
    uint32_t w = 0;
    for (int q = 0; q < wid; q++) w += lds16[q];
    __syncthreads();
    return v + w;
}

__device__ __forceinline__ bool iou_hit(float bx1, float by1, float bx2, float by2, float ca,
                                        float4 sv) {
    float xx1 = fmaxf(bx1, sv.x), yy1 = fmaxf(by1, sv.y);
    float xx2 = fminf(bx2, sv.z), yy2 = fminf(by2, sv.w);
    float inter = fmaxf(xx2 - xx1, 0.f) * fmaxf(yy2 - yy1, 0.f);
    float sa = (sv.z - sv.x) * (sv.w - sv.y);
    float un = ca + sa - inter;
    return (un > 0.f) && (inter / un > 0.7f);
}

// ---- kernel 1: per-(b,l) score histogram ----
__global__ __launch_bounds__(1024)
void k_keys(const float* __restrict__ c0, const float* __restrict__ c1,
            const float* __restrict__ c2, const float* __restrict__ c3,
            const float* __restrict__ c4, uint32_t* __restrict__ hist) {
    int t = threadIdx.x;
    int base = blockIdx.x * 1024;
    int gid = base + t;
    bool in = gid < MEMTOT;
    __shared__ uint32_t lh[NBIN];

    int bl = 0, b, n;
    uint32_t u = 0;
    if (in) {
        mem_decompose(gid, b, n, bl);
        float sv = read_cls(gid, c0, c1, c2, c3, c4);
        u = __float_as_uint(sv);
        u ^= (u >> 31) ? 0xFFFFFFFFu : 0x80000000u;    // monotonic float->uint
    }
    int blf = classify_bl(base);
    int bll = classify_bl(min(base + 1023, MEMTOT - 1));
    if (blf == bll) {
        for (int j = t; j < NBIN; j += 1024) lh[j] = 0u;
        __syncthreads();
        if (in) atomicAdd(&lh[u >> 20], 1u);
        __syncthreads();
        uint32_t* gh = hist + (size_t)blf * NBIN;
        for (int j = t; j < NBIN; j += 1024) {
            uint32_t v = lh[j];
            if (v) atomicAdd(&gh[j], v);
        }
    } else {
        if (in) atomicAdd(&hist[(size_t)bl * NBIN + (u >> 20)], 1u);
    }
}

// ---- kernel 2: per-(b,l) threshold bin + remainder ----
__global__ void k_bins(const uint32_t* __restrict__ hist, int* __restrict__ binT,
                       int* __restrict__ rrem) {
    int bl = blockIdx.x;             // 40 blocks
    const uint32_t* h = hist + (size_t)bl * NBIN;
    int l = bl % 5;
    uint32_t k = (l == 4) ? 741u : 2000u;
    __shared__ uint32_t ts[256];
    __shared__ uint32_t sb[256];
    int t = threadIdx.x;             // 256 threads, 16 bins each
    uint32_t hh[16];
#pragma unroll
    for (int i = 0; i < 16; i++) hh[i] = h[t * 16 + i];
    uint32_t s = 0;
#pragma unroll
    for (int i = 0; i < 16; i++) s += hh[i];
    ts[t] = s; sb[t] = s;
    __syncthreads();
    for (int d = 1; d < 256; d <<= 1) {
        uint32_t add = (t + d < 256) ? sb[t + d] : 0u;
        __syncthreads();
        sb[t] += add;
        __syncthreads();
    }
    uint32_t inc = sb[t], excl = inc - ts[t];
    if (excl < k && inc >= k) {
        uint32_t cum = excl;
#pragma unroll
        for (int i = 15; i >= 0; i--) {
            if (cum + hh[i] >= k) { binT[bl] = t * 16 + i; rrem[bl] = (int)(k - cum); break; }
            cum += hh[i];
        }
    }
}

// ---- kernel 3: wide compact from cls (mem-order, recompute key) ----
__global__ __launch_bounds__(1024)
void k_compact(const float* __restrict__ c0, const float* __restrict__ c1,
               const float* __restrict__ c2, const float* __restrict__ c3,
               const float* __restrict__ c4, const int* __restrict__ binT,
               uint32_t* __restrict__ keep_n, uint32_t* __restrict__ keep_u,
               uint32_t* __restrict__ keep_cnt,
               uint32_t* __restrict__ cand_n, uint32_t* __restrict__ cand_u,
               uint32_t* __restrict__ cand_cnt) {
    int gid = blockIdx.x * 1024 + threadIdx.x;
    bool in = gid < MEMTOT;
    int b = 0, n = 0, bl = 0;
    uint32_t u = 0;
    if (in) {
        mem_decompose(gid, b, n, bl);
        float sv = read_cls(gid, c0, c1, c2, c3, c4);
        u = __float_as_uint(sv);
        u ^= (u >> 31) ? 0xFFFFFFFFu : 0x80000000u;
    }
    int T = in ? binT[bl] : 0x7FFFFFFF;
    int bin = (int)(u >> 20);
    bool pk = in && (bin > T);
    bool pc = in && (bin == T);
    int lane = threadIdx.x & 63;

    unsigned long long act = __ballot(in);
    if (act == 0ull) return;
    int lead = __ffsll(act) - 1;
    int bl0 = __shfl(bl, lead, 64);
    bool unif = (__ballot(in && (bl == bl0)) == act);
    if (unif) {
        int b0 = bl0 / 5, l0 = bl0 % 5;
        uint32_t kbase = (uint32_t)(b0 * KTOT + l0 * 2000);
        unsigned long long mk = __ballot(pk);
        if (mk) {
            int leader = __ffsll(mk) - 1;
            uint32_t bs = 0;
            if (lane == leader) bs = atomicAdd(&keep_cnt[bl0 * CSTR], (uint32_t)__popcll(mk));
            bs = __shfl(bs, leader, 64);
            if (pk) {
                uint32_t p = kbase + bs + (uint32_t)__popcll(mk & ((1ull << lane) - 1ull));
                keep_n[p] = (uint32_t)n; keep_u[p] = u;
            }
        }
        unsigned long long mc = __ballot(pc);
        if (mc) {
            int leader = __ffsll(mc) - 1;
            uint32_t bs = 0;
            if (lane == leader) bs = atomicAdd(&cand_cnt[bl0 * CSTR], (uint32_t)__popcll(mc));
            bs = __shfl(bs, leader, 64);
            if (pc) {
                uint32_t p = bs + (uint32_t)__popcll(mc & ((1ull << lane) - 1ull));
                if (p < CAP) {
                    cand_n[(size_t)bl0 * CAP + p] = (uint32_t)n;
                    cand_u[(size_t)bl0 * CAP + p] = u;
                }
            }
        }
    } else {
        int b1 = bl / 5, l1 = bl % 5;
        if (pk) {
            uint32_t p = atomicAdd(&keep_cnt[bl * CSTR], 1u);
            uint32_t q = (uint32_t)(b1 * KTOT + l1 * 2000) + p;
            keep_n[q] = (uint32_t)n; keep_u[q] = u;
        }
        if (pc) {
            uint32_t p = atomicAdd(&cand_cnt[bl * CSTR], 1u);
            if (p < CAP) {
                cand_n[(size_t)bl * CAP + p] = (uint32_t)n;
                cand_u[(size_t)bl * CAP + p] = u;
            }
        }
    }
}

// ---- kernel 4: exact radix select over boundary candidates (52-bit, 5 passes) ----
__global__ __launch_bounds__(1024)
void k_select(const uint32_t* __restrict__ cand_n, const uint32_t* __restrict__ cand_u,
              const uint32_t* __restrict__ cand_cnt, const int* __restrict__ rrem,
              uint32_t* __restrict__ keep_n, uint32_t* __restrict__ keep_u,
              uint32_t* __restrict__ keep_cnt) {
    int bl = blockIdx.x;             // 40 blocks x 1024 threads
    int b = bl / 5, l = bl % 5;
    int C = (int)min(cand_cnt[bl * CSTR], (uint32_t)CAP);
    int r = rrem[bl];
    const uint32_t* cdn = cand_n + (size_t)bl * CAP;
    const uint32_t* cdu = cand_u + (size_t)bl * CAP;
    __shared__ uint32_t hist_l[2048];
    __shared__ uint32_t lds16[16];
    __shared__ unsigned long long pref_sh;
    __shared__ uint32_t kk_sh;
    int t = threadIdx.x;
    if (t == 0) { pref_sh = 0ull; kk_sh = (uint32_t)r; }
    unsigned long long maskAcc = 0ull;
    const int shifts[5] = {41, 30, 19, 8, 0};
    const uint32_t masks[5] = {0x7FFu, 0x7FFu, 0x7FFu, 0x7FFu, 0xFFu};
    __syncthreads();
    for (int p = 0; p < 5; p++) {
        int shift = shifts[p];
        uint32_t msk = masks[p];
        for (int j = t; j < 2048; j += 1024) hist_l[j] = 0u;
        __syncthreads();
        unsigned long long pref = pref_sh;
        uint32_t kk = kk_sh;
        for (int i = t; i < C; i += 1024) {
            unsigned long long key =
                ((unsigned long long)cdu[i] << 32) | (uint32_t)(~cdn[i]);
            if ((key & maskAcc) == pref)
                atomicAdd(&hist_l[(uint32_t)(key >> shift) & msk], 1u);
        }
        __syncthreads();
        uint32_t g = hist_l[2 * t] + hist_l[2 * t + 1];
        uint32_t inc = suffix_scan_1024(g, lds16, t);
        uint32_t excl = inc - g;
        if (excl < kk && inc >= kk) {
            uint32_t hh1 = hist_l[2 * t + 1];
            uint32_t digit, rem;
            if (excl + hh1 >= kk) { digit = 2 * t + 1; rem = kk - excl; }
            else { digit = 2 * t; rem = kk - (excl + hh1); }
            pref_sh = pref | ((unsigned long long)digit << shift);
            kk_sh = rem;
        }
        __syncthreads();
        maskAcc |= (unsigned long long)msk << shift;
    }
    unsigned long long Tk = pref_sh;
    __syncthreads();
    int lane = t & 63;
    for (int i0 = 0; i0 < C; i0 += 1024) {
        int i = i0 + t;
        bool in = i < C;
        uint32_t n = in ? cdn[i] : 0u;
        uint32_t u = in ? cdu[i] : 0u;
        unsigned long long key = in ?
            (((unsigned long long)u << 32) | (uint32_t)(~n)) : 0ull;
        bool pr = in && ((key & maskAcc) >= Tk);
        unsigned long long mk = __ballot(pr);
        if (mk) {
            int leader = __ffsll(mk) - 1;
            uint32_t bs = 0;
            if (lane == leader) bs = atomicAdd(&keep_cnt[bl * CSTR], (uint32_t)__popcll(mk));
            bs = __shfl(bs, leader, 64);
            if (pr) {
                uint32_t p = (uint32_t)(b * KTOT + l * 2000) + bs +
                             (uint32_t)__popcll(mk & ((1ull << lane) - 1ull));
                keep_n[p] = n; keep_u[p] = u;
            }
        }
    }
}

// ---- kernel 5: WIDE decode (per-image-aligned blocks, LDS hist) ----
__global__ __launch_bounds__(1024)
void k_decode(const float* __restrict__ b0, const float* __restrict__ b1,
              const float* __restrict__ b2, const float* __restrict__ b3,
              const float* __restrict__ b4, const float* __restrict__ anchors,
              const uint32_t* __restrict__ keep_n, const uint32_t* __restrict__ keep_u,
              float4* __restrict__ nbox, unsigned long long* __restrict__ nkey,
              uint32_t* __restrict__ shist) {
    int blk = blockIdx.x;
    int b = blk / DBLK, seg = blk % DBLK;
    int i = seg * 1024 + threadIdx.x;
    int t = threadIdx.x;
    __shared__ uint32_t lh[NBIN];
    for (int j = t; j < NBIN; j += 1024) lh[j] = 0u;
    __syncthreads();
    if (i < KTOT) {
        int gid = b * KTOT + i;
        int n = (int)keep_n[gid];
        uint32_t u = keep_u[gid];
        int l, H, W, loc; locate(n, l, H, W, loc);
        int a = loc % 3, hw = loc / 3;
        int w = hw % W, h = hw / W;
        const float* bp = (l == 0) ? b0 : (l == 1) ? b1 : (l == 2) ? b2 : (l == 3) ? b3 : b4;
        int HW = H * W;
        int base = ((b * 12 + a * 4) * H + h) * W + w;
        float dx = bp[base], dy = bp[base + HW];
        float dw = bp[base + 2 * HW], dh = bp[base + 3 * HW];
        float ax1 = anchors[4 * n], ay1 = anchors[4 * n + 1];
        float ax2 = anchors[4 * n + 2], ay2 = anchors[4 * n + 3];
        float wa = ax2 - ax1, ha = ay2 - ay1;
        float cxa = ax1 + 0.5f * wa, cya = ay1 + 0.5f * ha;
        const float CLIPV = 4.135166556742356f;    // log(1000/16)
        dw = fminf(dw, CLIPV); dh = fminf(dh, CLIPV);
        float cx = dx * wa + cxa, cy = dy * ha + cya;
        float pw = expf(dw) * wa, ph = expf(dh) * ha;
        float x1 = cx - 0.5f * pw, y1 = cy - 0.5f * ph;
        float x2 = cx + 0.5f * pw, y2 = cy + 0.5f * ph;
        x1 = fminf(fmaxf(x1, 0.f), 1216.f); x2 = fminf(fmaxf(x2, 0.f), 1216.f);
        y1 = fminf(fmaxf(y1, 0.f), 800.f);  y2 = fminf(fmaxf(y2, 0.f), 800.f);
        bool valid = ((x2 - x1) >= 1e-3f) && ((y2 - y1) >= 1e-3f);
        float off = (float)l * 1217.0f;            // max(IMG_H,IMG_W)+1
        nbox[gid] = make_float4(x1 + off, y1 + off, x2 + off, y2 + off);
        nkey[gid] = valid ? (((unsigned long long)u << 32) | (uint32_t)(~n)) : 0ull;
        if (valid) atomicAdd(&lh[u >> 20], 1u);
    }
    __syncthreads();
    uint32_t* gh = shist + (size_t)b * NBIN;
    for (int j = t; j < NBIN; j += 1024) {
        uint32_t v = lh[j];
        if (v) atomicAdd(&gh[j], v);
    }
}

// ---- kernel 6: fused bucket-scan + scatter + adaptive-batch sort + NMS ----
__global__ __launch_bounds__(1024)
void k_nms(const unsigned long long* __restrict__ nkey, const float4* __restrict__ nbox,
           const uint32_t* __restrict__ shist,
           unsigned long long* __restrict__ skey, float4* __restrict__ sbox,
           float* __restrict__ out) {
    int b = blockIdx.x, t = threadIdx.x, lane = t & 63, wid = t >> 6;
    unsigned long long* SK = skey + (size_t)b * KTOT;
    float4* BXs = sbox + (size_t)b * KTOT;

    __shared__ unsigned short bstart16[NBIN];       // 8 KB
    __shared__ unsigned short bcnt16[NBIN];         // 8 KB
    __shared__ unsigned long long k_l[BCAP];        // 16 KB
    __shared__ unsigned short p_l[BCAP];            // 4 KB
    __shared__ uint32_t scratch[4096];              // 16 KB (scur32 | hist2+scur2 | boxes+rows)
    __shared__ float4 sel_l[100];                   // 1.6 KB
    __shared__ uint32_t sup[SLICE / 32];
    __shared__ uint32_t lds16[16];
    __shared__ uint32_t V_sh, picks_sh, bend_sh, fat_sh;
    __shared__ unsigned long long gmax_sh;
    __shared__ uint32_t jpos_sh;
    __shared__ unsigned long long wred[16];

    // ---- phase A1: bucket suffix scan -> starts/counts (descending bucket order) ----
    const uint32_t* H = shist + (size_t)b * NBIN;
    uint32_t h0 = H[4 * t], h1 = H[4 * t + 1], h2 = H[4 * t + 2], h3 = H[4 * t + 3];
    uint32_t g = h0 + h1 + h2 + h3;
    uint32_t inc = suffix_scan_1024(g, lds16, t);
    if (t == 0) { V_sh = inc; picks_sh = 0u; }      // t=0 suffix = total valid
    uint32_t acc = inc - g;
    uint32_t* scur32 = scratch;
    bstart16[4 * t + 3] = (unsigned short)acc; bcnt16[4 * t + 3] = (unsigned short)h3;
    scur32[4 * t + 3] = acc; acc += h3;
    bstart16[4 * t + 2] = (unsigned short)acc; bcnt16[4 * t + 2] = (unsigned short)h2;
    scur32[4 * t + 2] = acc; acc += h2;
    bstart16[4 * t + 1] = (unsigned short)acc; bcnt16[4 * t + 1] = (unsigned short)h1;
    scur32[4 * t + 1] = acc; acc += h1;
    bstart16[4 * t + 0] = (unsigned short)acc; bcnt16[4 * t + 0] = (unsigned short)h0;
    scur32[4 * t + 0] = acc;
    __syncthreads();

    // ---- phase A2: scatter keys/boxes into bucket-descending global arrays ----
#pragma unroll
    for (int e = 0; e < DBLK; e++) {
        int i = t + e * 1024;
        if (i < KTOT) {
            unsigned long long kk = nkey[(size_t)b * KTOT + i];
            if (kk != 0ull) {
                uint32_t q = (uint32_t)(kk >> 52);
                uint32_t p = atomicAdd(&scur32[q], 1u);
                SK[p] = kk;
                BXs[p] = nbox[(size_t)b * KTOT + i];
            }
        }
    }
    __threadfence();
    __syncthreads();

    uint32_t V = V_sh;
    uint32_t picks = 0;
    uint32_t P = 0;
    while (P < V && picks < 100u) {
        // ---- batch end: all whole buckets fitting within BCAP keys ----
        uint32_t target = min(P + (uint32_t)BCAP, V);
        if (t == 0) { bend_sh = P; fat_sh = P; }
        __syncthreads();
        for (int q = t; q < NBIN; q += 1024) {
            uint32_t c = bcnt16[q];
            if (c) {
                uint32_t s = bstart16[q];
                if (s >= P && s + c <= target) atomicMax(&bend_sh, s + c);
                if (s == P) fat_sh = P + c;        // unique nonempty bucket at cursor
            }
        }
        __syncthreads();
        uint32_t B = bend_sh;

        if (B > P) {
            uint32_t total = B - P;                // <= BCAP
            // ---- level-2 bucket-relative bin sort (exact descending) ----
            uint32_t* hist2 = scratch;
            uint32_t* scur2 = scratch + 2048;
            for (int j = t; j < NB2; j += 1024) hist2[j] = 0u;
            __syncthreads();
            unsigned long long k0 = 0ull, k1 = 0ull;
            uint32_t bin0 = 0xFFFFFFFFu, bin1 = 0xFFFFFFFFu;
            uint32_t j0 = P + (uint32_t)t, j1 = P + (uint32_t)t + 1024u;
            if (j0 < B) {
                k0 = SK[j0];
                uint32_t q = (uint32_t)(k0 >> 52);
                uint32_t c = bcnt16[q], rel = (uint32_t)bstart16[q] - P;
                uint32_t sub = (uint32_t)((k0 >> 44) & 0xFFull);
                bin0 = rel + ((c * (255u - sub)) >> 8);
                atomicAdd(&hist2[bin0], 1u);
            }
            if (j1 < B) {
                k1 = SK[j1];
                uint32_t q = (uint32_t)(k1 >> 52);
                uint32_t c = bcnt16[q], rel = (uint32_t)bstart16[q] - P;
                uint32_t sub = (uint32_t)((k1 >> 44) & 0xFFull);
                bin1 = rel + ((c * (255u - sub)) >> 8);
                atomicAdd(&hist2[bin1], 1u);
            }
            __syncthreads();
            uint32_t g0 = hist2[2 * t], g1 = hist2[2 * t + 1];
            uint32_t incp = prefix_scan_1024(g0 + g1, lds16, t);
            uint32_t excl = incp - (g0 + g1);
            scur2[2 * t] = excl; scur2[2 * t + 1] = excl + g0;
            __syncthreads();
            if (bin0 != 0xFFFFFFFFu) {
                uint32_t pos = atomicAdd(&scur2[bin0], 1u);
                k_l[pos] = k0; p_l[pos] = (unsigned short)j0;
            }
            if (bin1 != 0xFFFFFFFFu) {
                uint32_t pos = atomicAdd(&scur2[bin1], 1u);
                k_l[pos] = k1; p_l[pos] = (unsigned short)j1;
            }
            __syncthreads();
            // collision fixup: per-bin desc insertion sort (exact, unique keys)
#pragma unroll
            for (int qq = 0; qq < 2; qq++) {
                uint32_t bin = 2 * (uint32_t)t + (uint32_t)qq;
                uint32_t c = hist2[bin];
                if (c > 1u) {
                    uint32_t st = scur2[bin] - c;
                    for (uint32_t a = st + 1; a < st + c; a++) {
                        unsigned long long kv = k_l[a]; unsigned short pv = p_l[a];
                        uint32_t w2 = a;
                        while (w2 > st && k_l[w2 - 1] < kv) {
                            k_l[w2] = k_l[w2 - 1]; p_l[w2] = p_l[w2 - 1]; w2--;
                        }
                        k_l[w2] = kv; p_l[w2] = pv;
                    }
                }
            }
            __syncthreads();

            // ---- slices of 256 with precomputed suppression matrix ----
            float* box_x = (float*)scratch;
            float* box_y = box_x + SLICE;
            float* box_z = box_y + SLICE;
            float* box_w = box_z + SLICE;
            uint32_t* rows = scratch + 1024;       // SLICE*RSTR = 2304 u32
            for (uint32_t s0 = 0; s0 < total && picks < 100u; s0 += SLICE) {
                uint32_t sl = min((uint32_t)SLICE, total - s0);
                __syncthreads();                    // scratch reuse guard
                if (t < SLICE) {
                    if (t < (int)sl) {
                        float4 cb = BXs[p_l[s0 + t]];
                        box_x[t] = cb.x; box_y[t] = cb.y; box_z[t] = cb.z; box_w[t] = cb.w;
                    } else {
                        box_x[t] = 0.f; box_y[t] = 0.f; box_z[t] = 0.f; box_w[t] = 0.f;
                    }
                }
                if (t < SLICE / 32) sup[t] = 0u;
                __syncthreads();
                // pre-suppression vs already-selected (unrolled x4, no break)
                if (picks > 0u && t < (int)sl) {
                    float bx1 = box_x[t], by1 = box_y[t], bx2 = box_z[t], by2 = box_w[t];
                    float ca = (bx2 - bx1) * (by2 - by1);
                    bool hit = false;
                    uint32_t s = 0;
                    for (; s + 4 <= picks; s += 4) {
                        float4 v0 = sel_l[s], v1 = sel_l[s + 1], v2 = sel_l[s + 2],
                               v3 = sel_l[s + 3];
                        hit = hit | iou_hit(bx1, by1, bx2, by2, ca, v0)
                                  | iou_hit(bx1, by1, bx2, by2, ca, v1)
                                  | iou_hit(bx1, by1, bx2, by2, ca, v2)
                                  | iou_hit(bx1, by1, bx2, by2, ca, v3);
                    }
                    for (; s < picks; s++) hit = hit | iou_hit(bx1, by1, bx2, by2, ca, sel_l[s]);
                    if (hit) atomicOr(&sup[t >> 5], 1u << (t & 31));
                }
                // build suppression matrix
                for (uint32_t widx = t; widx < SLICE * 8; widx += 1024) {
                    uint32_t i = widx & (SLICE - 1);
                    uint32_t wq = widx >> 8;
                    float bx1 = box_x[i], by1 = box_y[i], bx2 = box_z[i], by2 = box_w[i];
                    float ai = (bx2 - bx1) * (by2 - by1);
                    uint32_t jbase = wq * 32u, bits = 0u;
#pragma unroll
                    for (uint32_t qq = 0; qq < 32u; qq++) {
                        uint32_t jj = jbase + qq;
                        float jx1 = box_x[jj], jy1 = box_y[jj],
                              jx2 = box_z[jj], jy2 = box_w[jj];
                        float xx1 = fmaxf(bx1, jx1), yy1 = fmaxf(by1, jy1);
                        float xx2 = fminf(bx2, jx2), yy2 = fminf(by2, jy2);
                        float inter = fmaxf(xx2 - xx1, 0.f) * fmaxf(yy2 - yy1, 0.f);
                        float aj = (jx2 - jx1) * (jy2 - jy1);
                        float un = ai + aj - inter;
                        bool sp = (jj > i) && (un > 0.f) && (inter / un > 0.7f);
                        bits |= ((uint32_t)sp) << qq;
                    }
                    rows[i * RSTR + wq] = bits;
                }
                __syncthreads();
                // greedy sweep by wave 0 (pure bit ops)
                if (wid == 0) {
                    uint32_t myw = (lane < SLICE / 32) ? sup[lane] : 0u;
                    uint32_t pk = picks;
                    for (uint32_t i = 0; i < sl && pk < 100u; i++) {
                        uint32_t wv = __shfl(myw, (int)(i >> 5), 64);
                        if (!((wv >> (i & 31)) & 1u)) {
                            if (lane < SLICE / 32) myw |= rows[i * RSTR + lane];
                            if (lane == 0) {
                                float4 cb = make_float4(box_x[i], box_y[i], box_z[i], box_w[i]);
                                sel_l[pk] = cb;
                                unsigned long long mkey = k_l[s0 + i];
                                uint32_t n = ~(uint32_t)(mkey & 0xFFFFFFFFull);
                                float off = (float)level_of((int)n) * 1217.0f;
                                float* ob = out + ((size_t)b * 100 + pk) * 4;
                                ob[0] = cb.x - off; ob[1] = cb.y - off;
                                ob[2] = cb.z - off; ob[3] = cb.w - off;
                                uint32_t uu = (uint32_t)(mkey >> 32);
                                uint32_t sb2 = (uu & 0x80000000u) ? (uu ^ 0x80000000u) : ~uu;
                                out[3200 + b * 100 + pk] = __uint_as_float(sb2);
                            }
                            pk++;
                        }
                    }
                    if (lane == 0) picks_sh = pk;
                }
                __syncthreads();
                picks = picks_sh;
            }
            __syncthreads();
        } else {
            // ---- exact serial fallback over one oversized bucket [P, fat) ----
            B = fat_sh;
            uint32_t cnt = B - P;
            unsigned long long last = 0ull;
            bool first = true;
            for (uint32_t done = 0; done < cnt && picks < 100u; done++) {
                unsigned long long lbest = 0ull;
                uint32_t jbest = 0;
                for (uint32_t jj = P + t; jj < B; jj += 1024) {
                    unsigned long long kk = SK[jj];
                    if ((first || kk < last) && kk > lbest) { lbest = kk; jbest = jj; }
                }
                unsigned long long wm = lbest;
#pragma unroll
                for (int o2 = 32; o2 > 0; o2 >>= 1) {
                    unsigned long long oth = __shfl_down(wm, o2, 64);
                    if (oth > wm) wm = oth;
                }
                if (lane == 0) wred[wid] = wm;
                __syncthreads();
                if (t == 0) {
                    unsigned long long mm = wred[0];
                    for (int q = 1; q < 16; q++) if (wred[q] > mm) mm = wred[q];
                    gmax_sh = mm;
                }
                __syncthreads();
                unsigned long long gm = gmax_sh;
                if (gm == 0ull) break;
                if (lbest == gm) jpos_sh = jbest;
                __syncthreads();
                float4 cb = BXs[jpos_sh];
                float ca = (cb.z - cb.x) * (cb.w - cb.y);
                bool hit = false;
                for (uint32_t s = (uint32_t)lane; s < picks; s += 64u)
                    hit = hit | iou_hit(cb.x, cb.y, cb.z, cb.w, ca, sel_l[s]);
                bool selq = (__ballot(hit) == 0ull);
                if (selq) {
                    if (t == 0) {
                        sel_l[picks] = cb;
                        uint32_t n = ~(uint32_t)(gm & 0xFFFFFFFFull);
                        float off = (float)level_of((int)n) * 1217.0f;
                        float* ob = out + ((size_t)b * 100 + picks) * 4;
                        ob[0] = cb.x - off; ob[1] = cb.y - off;
                        ob[2] = cb.z - off; ob[3] = cb.w - off;
                        uint32_t uu = (uint32_t)(gm >> 32);
                        uint32_t sb2 = (uu & 0x80000000u) ? (uu ^ 0x80000000u) : ~uu;
                        out[3200 + b * 100 + picks] = __uint_as_float(sb2);
                    }
                    picks++;
                }
                last = gm; first = false;
                __syncthreads();
            }
        }
        P = B;
        __syncthreads();
    }
    // zero-fill unselected output slots
    for (uint32_t i = picks + (uint32_t)t; i < 100u; i += 1024u) {
        float* ob = out + ((size_t)b * 100 + i) * 4;
        ob[0] = 0.f; ob[1] = 0.f; ob[2] = 0.f; ob[3] = 0.f;
        out[3200 + b * 100 + i] = 0.f;
    }
}

extern "C" void kernel_launch(void* const* d_in, const int* in_sizes, int n_in,
                              void* d_out, int out_size, void* d_ws, size_t ws_size,
                              hipStream_t stream) {
    // setup_inputs() order: cls0, box0, cls1, box1, cls2, box2, cls3, box3, cls4, box4, anchors
    const float* cls[5] = { (const float*)d_in[0], (const float*)d_in[2], (const float*)d_in[4],
                            (const float*)d_in[6], (const float*)d_in[8] };
    const float* box[5] = { (const float*)d_in[1], (const float*)d_in[3], (const float*)d_in[5],
                            (const float*)d_in[7], (const float*)d_in[9] };
    const float* anchors = (const float*)d_in[10];
    float* out = (float*)d_out;

    // ---- workspace layout (u32 units). Zero blob first (one memset). ----
    uint32_t* W32 = (uint32_t*)d_ws;
    size_t o = 0;
    uint32_t* hist     = W32 + o; o += (size_t)40 * NBIN;      // 163840
    uint32_t* shist    = W32 + o; o += (size_t)BATCH * NBIN;   // 32768
    uint32_t* keep_cnt = W32 + o; o += 40 * CSTR;              // 640
    uint32_t* cand_cnt = W32 + o; o += 40 * CSTR;              // 640
    size_t zero_n = o;
    int*      binT     = (int*)(W32 + o); o += 64;
    int*      rrem     = (int*)(W32 + o); o += 64;
    uint32_t* keep_n   = W32 + o; o += (size_t)BATCH * KTOT;
    uint32_t* keep_u   = W32 + o; o += (size_t)BATCH * KTOT;
    uint32_t* cand_n   = W32 + o; o += (size_t)40 * CAP;
    uint32_t* cand_u   = W32 + o; o += (size_t)40 * CAP;
    o = (o + 3) & ~(size_t)3;                                  // 16B align
    float4* nbox = (float4*)(W32 + o); o += (size_t)BATCH * KTOT * 4;
    unsigned long long* nkey = (unsigned long long*)(W32 + o); o += (size_t)BATCH * KTOT * 2;
    float4* sbox = (float4*)(W32 + o); o += (size_t)BATCH * KTOT * 4;
    unsigned long long* skey = (unsigned long long*)(W32 + o); o += (size_t)BATCH * KTOT * 2;

    hipMemsetAsync(d_ws, 0, zero_n * sizeof(uint32_t), stream);
    k_keys<<<(MEMTOT + 1023) / 1024, 1024, 0, stream>>>(cls[0], cls[1], cls[2], cls[3], cls[4],
                                                        hist);
    k_bins<<<40, 256, 0, stream>>>(hist, binT, rrem);
    k_compact<<<(MEMTOT + 1023) / 1024, 1024, 0, stream>>>(cls[0], cls[1], cls[2], cls[3],
                                                           cls[4], binT, keep_n, keep_u,
                                                           keep_cnt, cand_n, cand_u, cand_cnt);
    k_select<<<40, 1024, 0, stream>>>(cand_n, cand_u, cand_cnt, rrem, keep_n, keep_u, keep_cnt);
    k_decode<<<BATCH * DBLK, 1024, 0, stream>>>(box[0], box[1], box[2], box[3], box[4],
                                                anchors, keep_n, keep_u, nbox, nkey, shist);
    k_nms<<<BATCH, 1024, 0, stream>>>(nkey, nbox, shist, skey, sbox, out);
}

// Round 12
// 135.088 us; speedup vs baseline: 1.4392x; 1.0945x over previous
//
#include <hip/hip_runtime.h>
#include <cstdint>

#define NTOT 242991
#define BATCH 8
#define KTOT 8741           // 2000*4 + 741
#define CAP 8192            // candidate buffer per (b,level)
#define NBIN 4096           // level-1 histogram bins (top 12 ordered bits)
#define CSTR 16             // counter padding stride
#define MEMTOT 1943928      // sum over levels of B*3*H*W  (== BATCH*NTOT)
#define SLICE 256           // suppression-matrix slice
#define RSTR 9              // rows stride (odd -> conflict-free)
#define BCAP 2048           // batch capacity (keys)
#define NB2 2048            // level-2 bins
#define DBLK 9              // ceil(KTOT/1024)

__device__ __forceinline__ int level_of(int n) {
    if (n < 182400) return 0;
    if (n < 228000) return 1;
    if (n < 239400) return 2;
    if (n < 242250) return 3;
    return 4;
}

__device__ __forceinline__ void locate(int n, int& l, int& H, int& W, int& loc) {
    if (n < 182400)      { l = 0; H = 200; W = 304; loc = n; }
    else if (n < 228000) { l = 1; H = 100; W = 152; loc = n - 182400; }
    else if (n < 239400) { l = 2; H = 50;  W = 76;  loc = n - 228000; }
    else if (n < 242250) { l = 3; H = 25;  W = 38;  loc = n - 239400; }
    else                 { l = 4; H = 13;  W = 19;  loc = n - 242250; }
}

__device__ __forceinline__ int classify_bl(int x) {
    int l, HW;
    if (x < 1459200)      { l = 0; HW = 60800; }
    else if (x < 1824000) { l = 1; HW = 15200; x -= 1459200; }
    else if (x < 1915200) { l = 2; HW = 3800;  x -= 1824000; }
    else if (x < 1938000) { l = 3; HW = 950;   x -= 1915200; }
    else                  { l = 4; HW = 247;   x -= 1938000; }
    return (x / (3 * HW)) * 5 + l;
}

__device__ __forceinline__ void mem_decompose(int x, int& b, int& n, int& bl) {
    int HW, off, l;
    if (x < 1459200)      { l = 0; HW = 60800; off = 0; }
    else if (x < 1824000) { l = 1; HW = 15200; off = 182400; x -= 1459200; }
    else if (x < 1915200) { l = 2; HW = 3800;  off = 228000; x -= 1824000; }
    else if (x < 1938000) { l = 3; HW = 950;   off = 239400; x -= 1915200; }
    else                  { l = 4; HW = 247;   off = 242250; x -= 1938000; }
    int seg = 3 * HW;
    b = x / seg; int r = x - b * seg;
    int a = r / HW, pix = r - a * HW;
    n = off + pix * 3 + a;
    bl = b * 5 + l;
}

__device__ __forceinline__ float read_cls(int gid, const float* c0, const float* c1,
                                          const float* c2, const float* c3, const float* c4) {
    return (gid < 1459200) ? c0[gid] :
           (gid < 1824000) ? c1[gid - 1459200] :
           (gid < 1915200) ? c2[gid - 1824000] :
           (gid < 1938000) ? c3[gid - 1915200] : c4[gid - 1938000];
}

// block-wide (1024 thr) inclusive SUFFIX scan (u32); 2 barriers
__device__ __forceinline__ uint32_t suffix_scan_1024(uint32_t g, uint32_t* lds16, int t) {
    int lane = t & 63, wid = t >> 6;
    uint32_t v = g;
#pragma unroll
    for (int o = 1; o < 64; o <<= 1) {
        uint32_t oth = __shfl_down(v, o, 64);
        if (lane + o < 64) v += oth;
    }
    if (lane == 0) lds16[wid] = v;
    __syncthreads();
    uint32_t w = 0;
    for (int q = wid + 1; q < 16; q++) w += lds16[q];
    __syncthreads();
    return v + w;
}

// block-wide inclusive PREFIX scan (u32); 2 barriers
__device__ __forceinline__ uint32_t prefix_scan_1024(uint32_t g, uint32_t* lds16, int t) {
    int lane = t & 63, wid = t >> 6;
    uint32_t v = g;
#pragma unroll
    for (int o = 1; o < 64; o <<= 1) {
        uint32_t oth = __shfl_up(v, o, 64);
        if (lane >= o) v += oth;
    }
    if (lane == 63) lds16[wid] = v;
    __syncthreads();
    uint32_t w = 0;
    for (int q = 0; q < wid; q++) w += lds16[q];
    __syncthreads();
    return v + w;
}

__device__ __forceinline__ bool iou_hit(float bx1, float by1, float bx2, float by2, float ca,
                                        float4 sv) {
    float xx1 = fmaxf(bx1, sv.x), yy1 = fmaxf(by1, sv.y);
    float xx2 = fminf(bx2, sv.z), yy2 = fminf(by2, sv.w);
    float inter = fmaxf(xx2 - xx1, 0.f) * fmaxf(yy2 - yy1, 0.f);
    float sa = (sv.z - sv.x) * (sv.w - sv.y);
    float un = ca + sa - inter;
    return (un > 0.f) && (inter / un > 0.7f);
}

// ---- kernel 1: per-(b,l) score histogram ----
__global__ __launch_bounds__(1024)
void k_keys(const float* __restrict__ c0, const float* __restrict__ c1,
            const float* __restrict__ c2, const float* __restrict__ c3,
            const float* __restrict__ c4, uint32_t* __restrict__ hist) {
    int t = threadIdx.x;
    int base = blockIdx.x * 1024;
    int gid = base + t;
    bool in = gid < MEMTOT;
    __shared__ uint32_t lh[NBIN];

    int bl = 0, b, n;
    uint32_t u = 0;
    if (in) {
        mem_decompose(gid, b, n, bl);
        float sv = read_cls(gid, c0, c1, c2, c3, c4);
        u = __float_as_uint(sv);
        u ^= (u >> 31) ? 0xFFFFFFFFu : 0x80000000u;    // monotonic float->uint
    }
    int blf = classify_bl(base);
    int bll = classify_bl(min(base + 1023, MEMTOT - 1));
    if (blf == bll) {
        for (int j = t; j < NBIN; j += 1024) lh[j] = 0u;
        __syncthreads();
        if (in) atomicAdd(&lh[u >> 20], 1u);
        __syncthreads();
        uint32_t* gh = hist + (size_t)blf * NBIN;
        for (int j = t; j < NBIN; j += 1024) {
            uint32_t v = lh[j];
            if (v) atomicAdd(&gh[j], v);
        }
    } else {
        if (in) atomicAdd(&hist[(size_t)bl * NBIN + (u >> 20)], 1u);
    }
}

// ---- kernel 2: per-(b,l) threshold bin + remainder ----
__global__ void k_bins(const uint32_t* __restrict__ hist, int* __restrict__ binT,
                       int* __restrict__ rrem) {
    int bl = blockIdx.x;             // 40 blocks
    const uint32_t* h = hist + (size_t)bl * NBIN;
    int l = bl % 5;
    uint32_t k = (l == 4) ? 741u : 2000u;
    __shared__ uint32_t ts[256];
    __shared__ uint32_t sb[256];
    int t = threadIdx.x;             // 256 threads, 16 bins each
    uint32_t hh[16];
#pragma unroll
    for (int i = 0; i < 16; i++) hh[i] = h[t * 16 + i];
    uint32_t s = 0;
#pragma unroll
    for (int i = 0; i < 16; i++) s += hh[i];
    ts[t] = s; sb[t] = s;
    __syncthreads();
    for (int d = 1; d < 256; d <<= 1) {
        uint32_t add = (t + d < 256) ? sb[t + d] : 0u;
        __syncthreads();
        sb[t] += add;
        __syncthreads();
    }
    uint32_t inc = sb[t], excl = inc - ts[t];
    if (excl < k && inc >= k) {
        uint32_t cum = excl;
#pragma unroll
        for (int i = 15; i >= 0; i--) {
            if (cum + hh[i] >= k) { binT[bl] = t * 16 + i; rrem[bl] = (int)(k - cum); break; }
            cum += hh[i];
        }
    }
}

// ---- kernel 3: wide compact from cls (mem-order, recompute key) ----
__global__ __launch_bounds__(1024)
void k_compact(const float* __restrict__ c0, const float* __restrict__ c1,
               const float* __restrict__ c2, const float* __restrict__ c3,
               const float* __restrict__ c4, const int* __restrict__ binT,
               uint32_t* __restrict__ keep_n, uint32_t* __restrict__ keep_u,
               uint32_t* __restrict__ keep_cnt,
               uint32_t* __restrict__ cand_n, uint32_t* __restrict__ cand_u,
               uint32_t* __restrict__ cand_cnt) {
    int gid = blockIdx.x * 1024 + threadIdx.x;
    bool in = gid < MEMTOT;
    int b = 0, n = 0, bl = 0;
    uint32_t u = 0;
    if (in) {
        mem_decompose(gid, b, n, bl);
        float sv = read_cls(gid, c0, c1, c2, c3, c4);
        u = __float_as_uint(sv);
        u ^= (u >> 31) ? 0xFFFFFFFFu : 0x80000000u;
    }
    int T = in ? binT[bl] : 0x7FFFFFFF;
    int bin = (int)(u >> 20);
    bool pk = in && (bin > T);
    bool pc = in && (bin == T);
    int lane = threadIdx.x & 63;

    unsigned long long act = __ballot(in);
    if (act == 0ull) return;
    int lead = __ffsll(act) - 1;
    int bl0 = __shfl(bl, lead, 64);
    bool unif = (__ballot(in && (bl == bl0)) == act);
    if (unif) {
        int b0 = bl0 / 5, l0 = bl0 % 5;
        uint32_t kbase = (uint32_t)(b0 * KTOT + l0 * 2000);
        unsigned long long mk = __ballot(pk);
        if (mk) {
            int leader = __ffsll(mk) - 1;
            uint32_t bs = 0;
            if (lane == leader) bs = atomicAdd(&keep_cnt[bl0 * CSTR], (uint32_t)__popcll(mk));
            bs = __shfl(bs, leader, 64);
            if (pk) {
                uint32_t p = kbase + bs + (uint32_t)__popcll(mk & ((1ull << lane) - 1ull));
                keep_n[p] = (uint32_t)n; keep_u[p] = u;
            }
        }
        unsigned long long mc = __ballot(pc);
        if (mc) {
            int leader = __ffsll(mc) - 1;
            uint32_t bs = 0;
            if (lane == leader) bs = atomicAdd(&cand_cnt[bl0 * CSTR], (uint32_t)__popcll(mc));
            bs = __shfl(bs, leader, 64);
            if (pc) {
                uint32_t p = bs + (uint32_t)__popcll(mc & ((1ull << lane) - 1ull));
                if (p < CAP) {
                    cand_n[(size_t)bl0 * CAP + p] = (uint32_t)n;
                    cand_u[(size_t)bl0 * CAP + p] = u;
                }
            }
        }
    } else {
        int b1 = bl / 5, l1 = bl % 5;
        if (pk) {
            uint32_t p = atomicAdd(&keep_cnt[bl * CSTR], 1u);
            uint32_t q = (uint32_t)(b1 * KTOT + l1 * 2000) + p;
            keep_n[q] = (uint32_t)n; keep_u[q] = u;
        }
        if (pc) {
            uint32_t p = atomicAdd(&cand_cnt[bl * CSTR], 1u);
            if (p < CAP) {
                cand_n[(size_t)bl * CAP + p] = (uint32_t)n;
                cand_u[(size_t)bl * CAP + p] = u;
            }
        }
    }
}

// ---- kernel 4: exact radix select over boundary candidates (52-bit, 5 passes) ----
__global__ __launch_bounds__(1024)
void k_select(const uint32_t* __restrict__ cand_n, const uint32_t* __restrict__ cand_u,
              const uint32_t* __restrict__ cand_cnt, const int* __restrict__ rrem,
              uint32_t* __restrict__ keep_n, uint32_t* __restrict__ keep_u,
              uint32_t* __restrict__ keep_cnt) {
    int bl = blockIdx.x;             // 40 blocks x 1024 threads
    int b = bl / 5, l = bl % 5;
    int C = (int)min(cand_cnt[bl * CSTR], (uint32_t)CAP);
    int r = rrem[bl];
    const uint32_t* cdn = cand_n + (size_t)bl * CAP;
    const uint32_t* cdu = cand_u + (size_t)bl * CAP;
    __shared__ uint32_t hist_l[2048];
    __shared__ uint32_t lds16[16];
    __shared__ unsigned long long pref_sh;
    __shared__ uint32_t kk_sh;
    int t = threadIdx.x;
    if (t == 0) { pref_sh = 0ull; kk_sh = (uint32_t)r; }
    unsigned long long maskAcc = 0ull;
    const int shifts[5] = {41, 30, 19, 8, 0};
    const uint32_t masks[5] = {0x7FFu, 0x7FFu, 0x7FFu, 0x7FFu, 0xFFu};
    __syncthreads();
    for (int p = 0; p < 5; p++) {
        int shift = shifts[p];
        uint32_t msk = masks[p];
        for (int j = t; j < 2048; j += 1024) hist_l[j] = 0u;
        __syncthreads();
        unsigned long long pref = pref_sh;
        uint32_t kk = kk_sh;
        for (int i = t; i < C; i += 1024) {
            unsigned long long key =
                ((unsigned long long)cdu[i] << 32) | (uint32_t)(~cdn[i]);
            if ((key & maskAcc) == pref)
                atomicAdd(&hist_l[(uint32_t)(key >> shift) & msk], 1u);
        }
        __syncthreads();
        uint32_t g = hist_l[2 * t] + hist_l[2 * t + 1];
        uint32_t inc = suffix_scan_1024(g, lds16, t);
        uint32_t excl = inc - g;
        if (excl < kk && inc >= kk) {
            uint32_t hh1 = hist_l[2 * t + 1];
            uint32_t digit, rem;
            if (excl + hh1 >= kk) { digit = 2 * t + 1; rem = kk - excl; }
            else { digit = 2 * t; rem = kk - (excl + hh1); }
            pref_sh = pref | ((unsigned long long)digit << shift);
            kk_sh = rem;
        }
        __syncthreads();
        maskAcc |= (unsigned long long)msk << shift;
    }
    unsigned long long Tk = pref_sh;
    __syncthreads();
    int lane = t & 63;
    for (int i0 = 0; i0 < C; i0 += 1024) {
        int i = i0 + t;
        bool in = i < C;
        uint32_t n = in ? cdn[i] : 0u;
        uint32_t u = in ? cdu[i] : 0u;
        unsigned long long key = in ?
            (((unsigned long long)u << 32) | (uint32_t)(~n)) : 0ull;
        bool pr = in && ((key & maskAcc) >= Tk);
        unsigned long long mk = __ballot(pr);
        if (mk) {
            int leader = __ffsll(mk) - 1;
            uint32_t bs = 0;
            if (lane == leader) bs = atomicAdd(&keep_cnt[bl * CSTR], (uint32_t)__popcll(mk));
            bs = __shfl(bs, leader, 64);
            if (pr) {
                uint32_t p = (uint32_t)(b * KTOT + l * 2000) + bs +
                             (uint32_t)__popcll(mk & ((1ull << lane) - 1ull));
                keep_n[p] = n; keep_u[p] = u;
            }
        }
    }
}

// ---- kernel 5: WIDE decode (per-image-aligned blocks, LDS hist) ----
__global__ __launch_bounds__(1024)
void k_decode(const float* __restrict__ b0, const float* __restrict__ b1,
              const float* __restrict__ b2, const float* __restrict__ b3,
              const float* __restrict__ b4, const float* __restrict__ anchors,
              const uint32_t* __restrict__ keep_n, const uint32_t* __restrict__ keep_u,
              float4* __restrict__ nbox, unsigned long long* __restrict__ nkey,
              uint32_t* __restrict__ shist) {
    int blk = blockIdx.x;
    int b = blk / DBLK, seg = blk % DBLK;
    int i = seg * 1024 + threadIdx.x;
    int t = threadIdx.x;
    __shared__ uint32_t lh[NBIN];
    for (int j = t; j < NBIN; j += 1024) lh[j] = 0u;
    __syncthreads();
    if (i < KTOT) {
        int gid = b * KTOT + i;
        int n = (int)keep_n[gid];
        uint32_t u = keep_u[gid];
        int l, H, W, loc; locate(n, l, H, W, loc);
        int a = loc % 3, hw = loc / 3;
        int w = hw % W, h = hw / W;
        const float* bp = (l == 0) ? b0 : (l == 1) ? b1 : (l == 2) ? b2 : (l == 3) ? b3 : b4;
        int HW = H * W;
        int base = ((b * 12 + a * 4) * H + h) * W + w;
        float dx = bp[base], dy = bp[base + HW];
        float dw = bp[base + 2 * HW], dh = bp[base + 3 * HW];
        float ax1 = anchors[4 * n], ay1 = anchors[4 * n + 1];
        float ax2 = anchors[4 * n + 2], ay2 = anchors[4 * n + 3];
        float wa = ax2 - ax1, ha = ay2 - ay1;
        float cxa = ax1 + 0.5f * wa, cya = ay1 + 0.5f * ha;
        const float CLIPV = 4.135166556742356f;    // log(1000/16)
        dw = fminf(dw, CLIPV); dh = fminf(dh, CLIPV);
        float cx = dx * wa + cxa, cy = dy * ha + cya;
        float pw = expf(dw) * wa, ph = expf(dh) * ha;
        float x1 = cx - 0.5f * pw, y1 = cy - 0.5f * ph;
        float x2 = cx + 0.5f * pw, y2 = cy + 0.5f * ph;
        x1 = fminf(fmaxf(x1, 0.f), 1216.f); x2 = fminf(fmaxf(x2, 0.f), 1216.f);
        y1 = fminf(fmaxf(y1, 0.f), 800.f);  y2 = fminf(fmaxf(y2, 0.f), 800.f);
        bool valid = ((x2 - x1) >= 1e-3f) && ((y2 - y1) >= 1e-3f);
        float off = (float)l * 1217.0f;            // max(IMG_H,IMG_W)+1
        nbox[gid] = make_float4(x1 + off, y1 + off, x2 + off, y2 + off);
        nkey[gid] = valid ? (((unsigned long long)u << 32) | (uint32_t)(~n)) : 0ull;
        if (valid) atomicAdd(&lh[u >> 20], 1u);
    }
    __syncthreads();
    uint32_t* gh = shist + (size_t)b * NBIN;
    for (int j = t; j < NBIN; j += 1024) {
        uint32_t v = lh[j];
        if (v) atomicAdd(&gh[j], v);
    }
}

// ---- kernel 6: scatter-free batch sort + suppression-matrix NMS ----
__global__ __launch_bounds__(1024)
void k_nms(const unsigned long long* __restrict__ nkey, const float4* __restrict__ nbox,
           const uint32_t* __restrict__ shist, float* __restrict__ out) {
    int b = blockIdx.x, t = threadIdx.x, lane = t & 63, wid = t >> 6;
    const unsigned long long* NK = nkey + (size_t)b * KTOT;
    const float4* NB = nbox + (size_t)b * KTOT;

    __shared__ unsigned short bstart16[NBIN];       // 8 KB
    __shared__ unsigned short bcnt16[NBIN];         // 8 KB
    __shared__ unsigned long long k_l[BCAP];        // 16 KB
    __shared__ unsigned short p_l[BCAP];            // 4 KB (original index payload)
    __shared__ uint32_t scratch[4096];              // 16 KB (hist2+scur2 | boxes+rows)
    __shared__ float4 sel_l[100];                   // 1.6 KB
    __shared__ uint32_t sup[SLICE / 32];
    __shared__ uint32_t lds16[16];
    __shared__ uint32_t V_sh, picks_sh, bend_sh, fat_sh;
    __shared__ unsigned long long gmax_sh;
    __shared__ uint32_t jpos_sh;
    __shared__ unsigned long long wred[16];

    // ---- phase A: bucket suffix scan -> starts/counts (descending bucket order) ----
    const uint32_t* H = shist + (size_t)b * NBIN;
    uint32_t h0 = H[4 * t], h1 = H[4 * t + 1], h2 = H[4 * t + 2], h3 = H[4 * t + 3];
    uint32_t g = h0 + h1 + h2 + h3;
    uint32_t inc = suffix_scan_1024(g, lds16, t);
    if (t == 0) { V_sh = inc; picks_sh = 0u; }      // t=0 suffix = total valid
    uint32_t acc = inc - g;
    bstart16[4 * t + 3] = (unsigned short)acc; bcnt16[4 * t + 3] = (unsigned short)h3; acc += h3;
    bstart16[4 * t + 2] = (unsigned short)acc; bcnt16[4 * t + 2] = (unsigned short)h2; acc += h2;
    bstart16[4 * t + 1] = (unsigned short)acc; bcnt16[4 * t + 1] = (unsigned short)h1; acc += h1;
    bstart16[4 * t + 0] = (unsigned short)acc; bcnt16[4 * t + 0] = (unsigned short)h0;
    __syncthreads();

    uint32_t V = V_sh;
    uint32_t picks = 0;
    uint32_t P = 0;
    while (P < V && picks < 100u) {
        // ---- batch end: all whole buckets fitting within BCAP keys ----
        uint32_t target = min(P + (uint32_t)BCAP, V);
        if (t == 0) { bend_sh = P; fat_sh = P; }
        __syncthreads();
        {
            uint32_t lmax = P;
            for (int q = t; q < NBIN; q += 1024) {
                uint32_t c = bcnt16[q];
                if (c) {
                    uint32_t s = bstart16[q];
                    if (s >= P && s + c <= target) lmax = max(lmax, s + c);
                    if (s == P) fat_sh = P + c;    // unique nonempty bucket at cursor
                }
            }
#pragma unroll
            for (int o = 32; o > 0; o >>= 1) {
                uint32_t oth = __shfl_down(lmax, o, 64);
                lmax = max(lmax, oth);
            }
            if (lane == 0) atomicMax(&bend_sh, lmax);
        }
        __syncthreads();
        uint32_t B = bend_sh;

        if (B > P) {
            uint32_t total = B - P;                // <= BCAP
            uint32_t* hist2 = scratch;
            uint32_t* scur2 = scratch + 2048;
            for (int j = t; j < NB2; j += 1024) hist2[j] = 0u;
            __syncthreads();
            // ---- pass 1 over nkey: count level-2 bins (batch keys only) ----
#pragma unroll
            for (int e = 0; e < DBLK; e++) {
                int i = t + e * 1024;
                if (i < KTOT) {
                    unsigned long long kk = NK[i];
                    if (kk != 0ull) {
                        uint32_t q = (uint32_t)(kk >> 52);
                        uint32_t s = bstart16[q];
                        if (s >= P && s < B) {
                            uint32_t c = bcnt16[q];
                            uint32_t sub = (uint32_t)((kk >> 44) & 0xFFull);
                            uint32_t bin = (s - P) + ((c * (255u - sub)) >> 8);
                            atomicAdd(&hist2[bin], 1u);
                        }
                    }
                }
            }
            __syncthreads();
            uint32_t g0 = hist2[2 * t], g1 = hist2[2 * t + 1];
            uint32_t incp = prefix_scan_1024(g0 + g1, lds16, t);
            uint32_t excl = incp - (g0 + g1);
            scur2[2 * t] = excl; scur2[2 * t + 1] = excl + g0;
            __syncthreads();
            // ---- pass 2 over nkey: scatter into LDS (payload = original idx) ----
#pragma unroll
            for (int e = 0; e < DBLK; e++) {
                int i = t + e * 1024;
                if (i < KTOT) {
                    unsigned long long kk = NK[i];
                    if (kk != 0ull) {
                        uint32_t q = (uint32_t)(kk >> 52);
                        uint32_t s = bstart16[q];
                        if (s >= P && s < B) {
                            uint32_t c = bcnt16[q];
                            uint32_t sub = (uint32_t)((kk >> 44) & 0xFFull);
                            uint32_t bin = (s - P) + ((c * (255u - sub)) >> 8);
                            uint32_t pos = atomicAdd(&scur2[bin], 1u);
                            k_l[pos] = kk; p_l[pos] = (unsigned short)i;
                        }
                    }
                }
            }
            __syncthreads();
            // ---- collision fixup: per-bin desc insertion sort (exact, unique keys) ----
#pragma unroll
            for (int qq = 0; qq < 2; qq++) {
                uint32_t bin = 2 * (uint32_t)t + (uint32_t)qq;
                uint32_t c = hist2[bin];
                if (c > 1u) {
                    uint32_t st = scur2[bin] - c;
                    for (uint32_t a = st + 1; a < st + c; a++) {
                        unsigned long long kv = k_l[a]; unsigned short pv = p_l[a];
                        uint32_t w2 = a;
                        while (w2 > st && k_l[w2 - 1] < kv) {
                            k_l[w2] = k_l[w2 - 1]; p_l[w2] = p_l[w2 - 1]; w2--;
                        }
                        k_l[w2] = kv; p_l[w2] = pv;
                    }
                }
            }
            __syncthreads();

            // ---- slices of 256 with precomputed suppression matrix ----
            float* box_x = (float*)scratch;
            float* box_y = box_x + SLICE;
            float* box_z = box_y + SLICE;
            float* box_w = box_z + SLICE;
            uint32_t* rows = scratch + 1024;       // SLICE*RSTR = 2304 u32
            for (uint32_t s0 = 0; s0 < total && picks < 100u; s0 += SLICE) {
                uint32_t sl = min((uint32_t)SLICE, total - s0);
                __syncthreads();                    // scratch reuse guard
                if (t < SLICE) {
                    if (t < (int)sl) {
                        float4 cb = NB[p_l[s0 + t]];
                        box_x[t] = cb.x; box_y[t] = cb.y; box_z[t] = cb.z; box_w[t] = cb.w;
                    } else {
                        box_x[t] = 0.f; box_y[t] = 0.f; box_z[t] = 0.f; box_w[t] = 0.f;
                    }
                }
                if (t < SLICE / 32) sup[t] = 0u;
                __syncthreads();
                // pre-suppression vs already-selected (unrolled x4, no break)
                if (picks > 0u && t < (int)sl) {
                    float bx1 = box_x[t], by1 = box_y[t], bx2 = box_z[t], by2 = box_w[t];
                    float ca = (bx2 - bx1) * (by2 - by1);
                    bool hit = false;
                    uint32_t s = 0;
                    for (; s + 4 <= picks; s += 4) {
                        float4 v0 = sel_l[s], v1 = sel_l[s + 1], v2 = sel_l[s + 2],
                               v3 = sel_l[s + 3];
                        hit = hit | iou_hit(bx1, by1, bx2, by2, ca, v0)
                                  | iou_hit(bx1, by1, bx2, by2, ca, v1)
                                  | iou_hit(bx1, by1, bx2, by2, ca, v2)
                                  | iou_hit(bx1, by1, bx2, by2, ca, v3);
                    }
                    for (; s < picks; s++) hit = hit | iou_hit(bx1, by1, bx2, by2, ca, sel_l[s]);
                    if (hit) atomicOr(&sup[t >> 5], 1u << (t & 31));
                }
                // build suppression matrix
                for (uint32_t widx = t; widx < SLICE * 8; widx += 1024) {
                    uint32_t i = widx & (SLICE - 1);
                    uint32_t wq = widx >> 8;
                    float bx1 = box_x[i], by1 = box_y[i], bx2 = box_z[i], by2 = box_w[i];
                    float ai = (bx2 - bx1) * (by2 - by1);
                    uint32_t jbase = wq * 32u, bits = 0u;
#pragma unroll
                    for (uint32_t qq = 0; qq < 32u; qq++) {
                        uint32_t jj = jbase + qq;
                        float jx1 = box_x[jj], jy1 = box_y[jj],
                              jx2 = box_z[jj], jy2 = box_w[jj];
                        float xx1 = fmaxf(bx1, jx1), yy1 = fmaxf(by1, jy1);
                        float xx2 = fminf(bx2, jx2), yy2 = fminf(by2, jy2);
                        float inter = fmaxf(xx2 - xx1, 0.f) * fmaxf(yy2 - yy1, 0.f);
                        float aj = (jx2 - jx1) * (jy2 - jy1);
                        float un = ai + aj - inter;
                        bool sp = (jj > i) && (un > 0.f) && (inter / un > 0.7f);
                        bits |= ((uint32_t)sp) << qq;
                    }
                    rows[i * RSTR + wq] = bits;
                }
                __syncthreads();
                // greedy sweep by wave 0 (pure bit ops)
                if (wid == 0) {
                    uint32_t myw = (lane < SLICE / 32) ? sup[lane] : 0u;
                    uint32_t pk = picks;
                    for (uint32_t i = 0; i < sl && pk < 100u; i++) {
                        uint32_t wv = __shfl(myw, (int)(i >> 5), 64);
                        if (!((wv >> (i & 31)) & 1u)) {
                            if (lane < SLICE / 32) myw |= rows[i * RSTR + lane];
                            if (lane == 0) {
                                float4 cb = make_float4(box_x[i], box_y[i], box_z[i], box_w[i]);
                                sel_l[pk] = cb;
                                unsigned long long mkey = k_l[s0 + i];
                                uint32_t n = ~(uint32_t)(mkey & 0xFFFFFFFFull);
                                float off = (float)level_of((int)n) * 1217.0f;
                                float* ob = out + ((size_t)b * 100 + pk) * 4;
                                ob[0] = cb.x - off; ob[1] = cb.y - off;
                                ob[2] = cb.z - off; ob[3] = cb.w - off;
                                uint32_t uu = (uint32_t)(mkey >> 32);
                                uint32_t sb2 = (uu & 0x80000000u) ? (uu ^ 0x80000000u) : ~uu;
                                out[3200 + b * 100 + pk] = __uint_as_float(sb2);
                            }
                            pk++;
                        }
                    }
                    if (lane == 0) picks_sh = pk;
                }
                __syncthreads();
                picks = picks_sh;
            }
            __syncthreads();
        } else {
            // ---- exact serial fallback over one oversized bucket at cursor P ----
            B = fat_sh;
            uint32_t cnt = B - P;
            unsigned short Pw = (unsigned short)P;
            unsigned long long last = 0ull;
            bool first = true;
            for (uint32_t done = 0; done < cnt && picks < 100u; done++) {
                unsigned long long lbest = 0ull;
                uint32_t jbest = 0;
                for (uint32_t jj = t; jj < KTOT; jj += 1024) {
                    unsigned long long kk = NK[jj];
                    if (kk != 0ull && bstart16[(uint32_t)(kk >> 52)] == Pw &&
                        (first || kk < last) && kk > lbest) { lbest = kk; jbest = jj; }
                }
                unsigned long long wm = lbest;
#pragma unroll
                for (int o2 = 32; o2 > 0; o2 >>= 1) {
                    unsigned long long oth = __shfl_down(wm, o2, 64);
                    if (oth > wm) wm = oth;
                }
                if (lane == 0) wred[wid] = wm;
                __syncthreads();
                if (t == 0) {
                    unsigned long long mm = wred[0];
                    for (int q = 1; q < 16; q++) if (wred[q] > mm) mm = wred[q];
                    gmax_sh = mm;
                }
                __syncthreads();
                unsigned long long gm = gmax_sh;
                if (gm == 0ull) break;
                if (lbest == gm) jpos_sh = jbest;
                __syncthreads();
                float4 cb = NB[jpos_sh];
                float ca = (cb.z - cb.x) * (cb.w - cb.y);
                bool hit = false;
                for (uint32_t s = (uint32_t)lane; s < picks; s += 64u)
                    hit = hit | iou_hit(cb.x, cb.y, cb.z, cb.w, ca, sel_l[s]);
                bool selq = (__ballot(hit) == 0ull);
                if (selq) {
                    if (t == 0) {
                        sel_l[picks] = cb;
                        uint32_t n = ~(uint32_t)(gm & 0xFFFFFFFFull);
                        float off = (float)level_of((int)n) * 1217.0f;
                        float* ob = out + ((size_t)b * 100 + picks) * 4;
                        ob[0] = cb.x - off; ob[1] = cb.y - off;
                        ob[2] = cb.z - off; ob[3] = cb.w - off;
                        uint32_t uu = (uint32_t)(gm >> 32);
                        uint32_t sb2 = (uu & 0x80000000u) ? (uu ^ 0x80000000u) : ~uu;
                        out[3200 + b * 100 + picks] = __uint_as_float(sb2);
                    }
                    picks++;
                }
                last = gm; first = false;
                __syncthreads();
            }
        }
        P = B;
        __syncthreads();
    }
    // zero-fill unselected output slots
    for (uint32_t i = picks + (uint32_t)t; i < 100u; i += 1024u) {
        float* ob = out + ((size_t)b * 100 + i) * 4;
        ob[0] = 0.f; ob[1] = 0.f; ob[2] = 0.f; ob[3] = 0.f;
        out[3200 + b * 100 + i] = 0.f;
    }
}

extern "C" void kernel_launch(void* const* d_in, const int* in_sizes, int n_in,
                              void* d_out, int out_size, void* d_ws, size_t ws_size,
                              hipStream_t stream) {
    // setup_inputs() order: cls0, box0, cls1, box1, cls2, box2, cls3, box3, cls4, box4, anchors
    const float* cls[5] = { (const float*)d_in[0], (const float*)d_in[2], (const float*)d_in[4],
                            (const float*)d_in[6], (const float*)d_in[8] };
    const float* box[5] = { (const float*)d_in[1], (const float*)d_in[3], (const float*)d_in[5],
                            (const float*)d_in[7], (const float*)d_in[9] };
    const float* anchors = (const float*)d_in[10];
    float* out = (float*)d_out;

    // ---- workspace layout (u32 units). Zero blob first (one memset). ----
    uint32_t* W32 = (uint32_t*)d_ws;
    size_t o = 0;
    uint32_t* hist     = W32 + o; o += (size_t)40 * NBIN;      // 163840
    uint32_t* shist    = W32 + o; o += (size_t)BATCH * NBIN;   // 32768
    uint32_t* keep_cnt = W32 + o; o += 40 * CSTR;              // 640
    uint32_t* cand_cnt = W32 + o; o += 40 * CSTR;              // 640
    size_t zero_n = o;
    int*      binT     = (int*)(W32 + o); o += 64;
    int*      rrem     = (int*)(W32 + o); o += 64;
    uint32_t* keep_n   = W32 + o; o += (size_t)BATCH * KTOT;
    uint32_t* keep_u   = W32 + o; o += (size_t)BATCH * KTOT;
    uint32_t* cand_n   = W32 + o; o += (size_t)40 * CAP;
    uint32_t* cand_u   = W32 + o; o += (size_t)40 * CAP;
    o = (o + 3) & ~(size_t)3;                                  // 16B align
    float4* nbox = (float4*)(W32 + o); o += (size_t)BATCH * KTOT * 4;
    unsigned long long* nkey = (unsigned long long*)(W32 + o); o += (size_t)BATCH * KTOT * 2;

    hipMemsetAsync(d_ws, 0, zero_n * sizeof(uint32_t), stream);
    k_keys<<<(MEMTOT + 1023) / 1024, 1024, 0, stream>>>(cls[0], cls[1], cls[2], cls[3], cls[4],
                                                        hist);
    k_bins<<<40, 256, 0, stream>>>(hist, binT, rrem);
    k_compact<<<(MEMTOT + 1023) / 1024, 1024, 0, stream>>>(cls[0], cls[1], cls[2], cls[3],
                                                           cls[4], binT, keep_n, keep_u,
                                                           keep_cnt, cand_n, cand_u, cand_cnt);
    k_select<<<40, 1024, 0, stream>>>(cand_n, cand_u, cand_cnt, rrem, keep_n, keep_u, keep_cnt);
    k_decode<<<BATCH * DBLK, 1024, 0, stream>>>(box[0], box[1], box[2], box[3], box[4],
                                                anchors, keep_n, keep_u, nbox, nkey, shist);
    k_nms<<<BATCH, 1024, 0, stream>>>(nkey, nbox, shist, out);
}